// Round 1
// baseline (4693.670 us; speedup 1.0000x reference)
//
#include <hip/hip_runtime.h>

namespace {

constexpr int HD  = 128;      // hidden dim
constexpr int NE  = 600000;   // edges per direction
constexpr int NDR = 200000;   // drugs
constexpr int NDI = 100000;   // diseases
constexpr int NB  = 8192;     // link batch

// ---------------- degree counts ----------------
__global__ void count_kernel(const int* __restrict__ dst, int n, int* __restrict__ cnt) {
  int i = blockIdx.x * 256 + threadIdx.x;
  if (i < n) atomicAdd(&cnt[dst[i]], 1);
}

// ---------------- edge scatter-add: agg[dst] += x[src] ----------------
// 32 threads per edge, float4 per thread.
__global__ void scatter_kernel(const float* __restrict__ x, const int* __restrict__ src,
                               const int* __restrict__ dst, float* __restrict__ agg, int nE) {
  int idx = blockIdx.x * 256 + threadIdx.x;
  int e = idx >> 5;
  if (e >= nE) return;
  int c = idx & 31;
  int s = src[e], d = dst[e];
  float4 v = reinterpret_cast<const float4*>(x + (size_t)s * HD)[c];
  float* o = agg + (size_t)d * HD + c * 4;
  atomicAdd(o + 0, v.x);
  atomicAdd(o + 1, v.y);
  atomicAdd(o + 2, v.z);
  atomicAdd(o + 3, v.w);
}

// ---------------- dual GEMM: Out = act(In1/cnt @ Wa^T + In2 @ Wb^T + bias) ----------
// Tile: 64 rows x 128 cols per block (blockIdx.y = 128-col slab). 256 threads,
// each computes 4 rows x 8 cols. K-chunks of 32 staged in LDS.
template <bool DUAL>
__global__ __launch_bounds__(256) void dual_gemm(
    const float* __restrict__ In1, const int* __restrict__ cnt,
    const float* __restrict__ In2,
    const float* __restrict__ Wa, const float* __restrict__ Wb,  // [J][K] row-major
    const float* __restrict__ bias,
    const int* __restrict__ map1, const int* __restrict__ map2,
    float* __restrict__ Out, int nRows, int K, int Jtot, int relu) {
  __shared__ float sIn1[64][36];                  // [r][k], stride 36 keeps 16B-aligned b128 writes
  __shared__ float sIn2[DUAL ? 64 : 1][36];
  __shared__ float sWa[32][132];                  // [k][j], stride 132 keeps b128 reads aligned
  __shared__ float sWb[DUAL ? 32 : 1][132];

  const int tid = threadIdx.x;
  const int row0 = blockIdx.x * 64;
  const int colSlab = blockIdx.y * 128;
  const int tr = (tid >> 4) * 4;   // compute: 16 row-groups x 4 rows
  const int tc = (tid & 15) * 8;   //          16 col-groups x 8 cols
  const int lr = tid >> 2;         // staging In: 64 rows x (4 thr x 8 floats)
  const int lk = (tid & 3) * 4;
  const int wj = tid >> 1;         // staging W: 128 rows x (2 thr x 16 floats)
  const int wk = (tid & 1) * 16;

  int re = row0 + lr;
  if (re > nRows - 1) re = nRows - 1;
  const int g1 = map1 ? map1[re] : re;
  const int g2 = (DUAL && map2) ? map2[re] : re;
  const float rs = cnt ? (1.0f / fmaxf((float)cnt[g1], 1.0f)) : 1.0f;

  float acc[4][8];
#pragma unroll
  for (int i = 0; i < 4; ++i)
#pragma unroll
    for (int j = 0; j < 8; ++j) acc[i][j] = bias[colSlab + tc + j];

  for (int kc = 0; kc < K; kc += 32) {
    {
      const float* p = In1 + (size_t)g1 * K + kc + lk;
      float4 v0 = *reinterpret_cast<const float4*>(p);
      float4 v1 = *reinterpret_cast<const float4*>(p + 16);
      sIn1[lr][lk + 0] = v0.x * rs;  sIn1[lr][lk + 1] = v0.y * rs;
      sIn1[lr][lk + 2] = v0.z * rs;  sIn1[lr][lk + 3] = v0.w * rs;
      sIn1[lr][lk + 16] = v1.x * rs; sIn1[lr][lk + 17] = v1.y * rs;
      sIn1[lr][lk + 18] = v1.z * rs; sIn1[lr][lk + 19] = v1.w * rs;
    }
    if (DUAL) {
      const float* p = In2 + (size_t)g2 * K + kc + lk;
      float4 v0 = *reinterpret_cast<const float4*>(p);
      float4 v1 = *reinterpret_cast<const float4*>(p + 16);
      sIn2[lr][lk + 0] = v0.x;  sIn2[lr][lk + 1] = v0.y;
      sIn2[lr][lk + 2] = v0.z;  sIn2[lr][lk + 3] = v0.w;
      sIn2[lr][lk + 16] = v1.x; sIn2[lr][lk + 17] = v1.y;
      sIn2[lr][lk + 18] = v1.z; sIn2[lr][lk + 19] = v1.w;
    }
    {
      const float* p = Wa + (size_t)(colSlab + wj) * K + kc + wk;
#pragma unroll
      for (int i = 0; i < 4; ++i) {
        float4 w = reinterpret_cast<const float4*>(p)[i];
        sWa[wk + i * 4 + 0][wj] = w.x;
        sWa[wk + i * 4 + 1][wj] = w.y;
        sWa[wk + i * 4 + 2][wj] = w.z;
        sWa[wk + i * 4 + 3][wj] = w.w;
      }
    }
    if (DUAL) {
      const float* p = Wb + (size_t)(colSlab + wj) * K + kc + wk;
#pragma unroll
      for (int i = 0; i < 4; ++i) {
        float4 w = reinterpret_cast<const float4*>(p)[i];
        sWb[wk + i * 4 + 0][wj] = w.x;
        sWb[wk + i * 4 + 1][wj] = w.y;
        sWb[wk + i * 4 + 2][wj] = w.z;
        sWb[wk + i * 4 + 3][wj] = w.w;
      }
    }
    __syncthreads();
#pragma unroll 4
    for (int k = 0; k < 32; ++k) {
      float a1[4];
#pragma unroll
      for (int i = 0; i < 4; ++i) a1[i] = sIn1[tr + i][k];
      float4 wa0 = *reinterpret_cast<const float4*>(&sWa[k][tc]);
      float4 wa1 = *reinterpret_cast<const float4*>(&sWa[k][tc + 4]);
      const float wav[8] = {wa0.x, wa0.y, wa0.z, wa0.w, wa1.x, wa1.y, wa1.z, wa1.w};
#pragma unroll
      for (int i = 0; i < 4; ++i)
#pragma unroll
        for (int j = 0; j < 8; ++j) acc[i][j] += a1[i] * wav[j];
      if (DUAL) {
        float a2[4];
#pragma unroll
        for (int i = 0; i < 4; ++i) a2[i] = sIn2[tr + i][k];
        float4 wb0 = *reinterpret_cast<const float4*>(&sWb[k][tc]);
        float4 wb1 = *reinterpret_cast<const float4*>(&sWb[k][tc + 4]);
        const float wbv[8] = {wb0.x, wb0.y, wb0.z, wb0.w, wb1.x, wb1.y, wb1.z, wb1.w};
#pragma unroll
        for (int i = 0; i < 4; ++i)
#pragma unroll
          for (int j = 0; j < 8; ++j) acc[i][j] += a2[i] * wbv[j];
      }
    }
    __syncthreads();
  }

  if (relu) {
#pragma unroll
    for (int i = 0; i < 4; ++i)
#pragma unroll
      for (int j = 0; j < 8; ++j) acc[i][j] = fmaxf(acc[i][j], 0.0f);
  }
#pragma unroll
  for (int i = 0; i < 4; ++i) {
    int r = row0 + tr + i;
    if (r < nRows) {
      float* po = Out + (size_t)r * Jtot + colSlab + tc;
      *reinterpret_cast<float4*>(po)     = make_float4(acc[i][0], acc[i][1], acc[i][2], acc[i][3]);
      *reinterpret_cast<float4*>(po + 4) = make_float4(acc[i][4], acc[i][5], acc[i][6], acc[i][7]);
    }
  }
}

// ---------------- fold attention (len-1 softmax == identity): Wfold = Wout @ Wv ------
__global__ void fold_attn(const float* __restrict__ Win, const float* __restrict__ bin,
                          const float* __restrict__ Wout, const float* __restrict__ bout,
                          float* __restrict__ Wfold, float* __restrict__ bfold) {
  int s = blockIdx.x >> 7, m = blockIdx.x & 127, k = threadIdx.x;
  const float* wout_row = Wout + ((size_t)s * HD + m) * HD;        // Wout[s][m][:]
  const float* wv = Win + (size_t)s * 3 * HD * HD + 2 * HD * HD;   // Wv[s][:][:]
  float acc = 0.0f;
  for (int u = 0; u < HD; ++u) acc += wout_row[u] * wv[u * HD + k];
  Wfold[((size_t)s * HD + m) * HD + k] = acc;
  if (k == 0) {
    const float* bv = bin + (size_t)s * 3 * HD + 2 * HD;
    float b = bout[s * HD + m];
    for (int u = 0; u < HD; ++u) b += wout_row[u] * bv[u];
    bfold[s * HD + m] = b;
  }
}

// ---------------- fold attn into MLP layer 1 ----------------
// h1 = relu(drug_emb @ A^T + dis_emb @ B^T + bc)
__global__ void fold_mlp(const float* __restrict__ W1, const float* __restrict__ b1,
                         const float* __restrict__ Wfold, const float* __restrict__ bfold,
                         float* __restrict__ A, float* __restrict__ Bm, float* __restrict__ bc) {
  int r = blockIdx.x, k = threadIdx.x;
  const float* w1r = W1 + (size_t)r * 512;
  const float* Wf0 = Wfold;            // module 0: drug_att <- dis_emb
  const float* Wf1 = Wfold + HD * HD;  // module 1: dis_att  <- drug_emb
  float accA = 0.0f, accB = 0.0f;
  for (int m = 0; m < HD; ++m) {
    accA += w1r[384 + m] * Wf1[m * HD + k];
    accB += w1r[256 + m] * Wf0[m * HD + k];
  }
  A[(size_t)r * HD + k]  = w1r[k] + accA;
  Bm[(size_t)r * HD + k] = w1r[128 + k] + accB;
  if (k == 0) {
    float b = b1[r];
    for (int m = 0; m < HD; ++m) b += w1r[256 + m] * bfold[m] + w1r[384 + m] * bfold[HD + m];
    bc[r] = b;
  }
}

// ---------------- final dot: out[b] = h2[b] . W3 + b3 ----------------
__global__ void final_dot(const float* __restrict__ h2, const float* __restrict__ W3,
                          const float* __restrict__ b3, float* __restrict__ out) {
  int b = blockIdx.x * 4 + (threadIdx.x >> 6);
  int lane = threadIdx.x & 63;
  float2 hv = reinterpret_cast<const float2*>(h2 + (size_t)b * HD)[lane];
  float2 wv = reinterpret_cast<const float2*>(W3)[lane];
  float v = hv.x * wv.x + hv.y * wv.y;
  for (int off = 32; off; off >>= 1) v += __shfl_down(v, off);
  if (lane == 0) out[b] = v + b3[0];
}

}  // namespace

extern "C" void kernel_launch(void* const* d_in, const int* in_sizes, int n_in,
                              void* d_out, int out_size, void* d_ws, size_t ws_size,
                              hipStream_t stream) {
  const int* src_d2di  = (const int*)d_in[0];
  const int* dst_d2di  = (const int*)d_in[1];
  const int* src_di2dr = (const int*)d_in[2];
  const int* dst_di2dr = (const int*)d_in[3];
  const int* drug_idx  = (const int*)d_in[4];
  const int* dis_idx   = (const int*)d_in[5];
  const float* emb_drug = (const float*)d_in[6];
  const float* emb_dis  = (const float*)d_in[7];
  const float* Wl = (const float*)d_in[8];
  const float* bl = (const float*)d_in[9];
  const float* Wr = (const float*)d_in[10];
  const float* attn_Win  = (const float*)d_in[11];
  const float* attn_bin  = (const float*)d_in[12];
  const float* attn_Wout = (const float*)d_in[13];
  const float* attn_bout = (const float*)d_in[14];
  const float* W1 = (const float*)d_in[15];
  const float* b1 = (const float*)d_in[16];
  const float* W2 = (const float*)d_in[17];
  const float* b2 = (const float*)d_in[18];
  const float* W3 = (const float*)d_in[19];
  const float* b3 = (const float*)d_in[20];
  float* out = (float*)d_out;

  // ---- workspace carve (floats) ----
  float* ws = (float*)d_ws;
  size_t off = 0;
  auto carve = [&](size_t n) { float* p = ws + off; off += n; return p; };
  int*   cnt_dis  = (int*)carve(NDI);
  int*   cnt_drug = (int*)carve(NDR);
  float* agg_dis  = carve((size_t)NDI * HD);   // layer0 dis agg, reused for layer1 (stack1)
  float* agg_drug = carve((size_t)NDR * HD);   // layer0 drug agg, reused for layer1 (stack0)
  float* dis1_s0  = carve((size_t)NDI * HD);   // dis1 (stack0), full: scatter source L1
  float* drug1_s1 = carve((size_t)NDR * HD);   // drug1 (stack1), full: scatter source L1
  float* drug1b   = carve((size_t)NB * HD);    // drug1 (stack0) at drug_idx rows
  float* dis1b    = carve((size_t)NB * HD);    // dis1 (stack1) at disease_idx rows
  float* drug_emb = carve((size_t)NB * HD);
  float* dis_emb  = carve((size_t)NB * HD);
  float* Wfold = carve(2 * HD * HD);
  float* bfold = carve(2 * HD);
  float* Am = carve(2 * HD * HD);
  float* Bmat = carve(2 * HD * HD);
  float* bc = carve(2 * HD);
  float* h1 = carve((size_t)NB * 2 * HD);
  float* h2 = carve((size_t)NB * HD);

  const size_t HH = (size_t)HD * HD;
  dim3 blk(256);

  // zero counts + both agg buffers (contiguous)
  hipMemsetAsync(cnt_dis, 0, ((size_t)NDI + NDR + ((size_t)NDI + NDR) * HD) * 4, stream);

  // weight folding (independent of graph work)
  fold_attn<<<256, 128, 0, stream>>>(attn_Win, attn_bin, attn_Wout, attn_bout, Wfold, bfold);
  fold_mlp<<<256, 128, 0, stream>>>(W1, b1, Wfold, bfold, Am, Bmat, bc);

  // degree counts
  count_kernel<<<(NE + 255) / 256, blk, 0, stream>>>(dst_d2di, NE, cnt_dis);
  count_kernel<<<(NE + 255) / 256, blk, 0, stream>>>(dst_di2dr, NE, cnt_drug);

  // layer-0 aggregations (shared across stacks)
  scatter_kernel<<<(NE * 32) / 256, blk, 0, stream>>>(emb_drug, src_d2di, dst_d2di, agg_dis, NE);
  scatter_kernel<<<(NE * 32) / 256, blk, 0, stream>>>(emb_dis, src_di2dr, dst_di2dr, agg_drug, NE);

  // layer-0 transforms
  // dis1_s0 (full, W[0][0][0])
  dual_gemm<true><<<dim3(1563, 1), blk, 0, stream>>>(agg_dis, cnt_dis, emb_dis,
      Wl + 0 * HH, Wr + 0 * HH, bl + 0 * HD, nullptr, nullptr, dis1_s0, NDI, 128, 128, 1);
  // drug1_s1 (full, W[1][0][1] -> idx 5)
  dual_gemm<true><<<dim3(3125, 1), blk, 0, stream>>>(agg_drug, cnt_drug, emb_drug,
      Wl + 5 * HH, Wr + 5 * HH, bl + 5 * HD, nullptr, nullptr, drug1_s1, NDR, 128, 128, 1);
  // drug1b (stack0 at drug_idx, W[0][0][1] -> idx 1)
  dual_gemm<true><<<dim3(128, 1), blk, 0, stream>>>(agg_drug, cnt_drug, emb_drug,
      Wl + 1 * HH, Wr + 1 * HH, bl + 1 * HD, drug_idx, drug_idx, drug1b, NB, 128, 128, 1);
  // dis1b (stack1 at disease_idx, W[1][0][0] -> idx 4)
  dual_gemm<true><<<dim3(128, 1), blk, 0, stream>>>(agg_dis, cnt_dis, emb_dis,
      Wl + 4 * HH, Wr + 4 * HH, bl + 4 * HD, dis_idx, dis_idx, dis1b, NB, 128, 128, 1);

  // re-zero agg buffers for layer 1
  hipMemsetAsync(agg_dis, 0, ((size_t)NDI + NDR) * HD * 4, stream);

  // layer-1 aggregations
  scatter_kernel<<<(NE * 32) / 256, blk, 0, stream>>>(dis1_s0, src_di2dr, dst_di2dr, agg_drug, NE);
  scatter_kernel<<<(NE * 32) / 256, blk, 0, stream>>>(drug1_s1, src_d2di, dst_d2di, agg_dis, NE);

  // layer-1 transforms (only at batch rows)
  // drug_emb = drug_x[drug_idx]  (W[0][1][1] -> idx 3)
  dual_gemm<true><<<dim3(128, 1), blk, 0, stream>>>(agg_drug, cnt_drug, drug1b,
      Wl + 3 * HH, Wr + 3 * HH, bl + 3 * HD, drug_idx, nullptr, drug_emb, NB, 128, 128, 1);
  // dis_emb = dis_x[disease_idx] (W[1][1][0] -> idx 6)
  dual_gemm<true><<<dim3(128, 1), blk, 0, stream>>>(agg_dis, cnt_dis, dis1b,
      Wl + 6 * HH, Wr + 6 * HH, bl + 6 * HD, dis_idx, nullptr, dis_emb, NB, 128, 128, 1);

  // link MLP (attention folded into Am/Bmat/bc)
  dual_gemm<true><<<dim3(128, 2), blk, 0, stream>>>(drug_emb, nullptr, dis_emb,
      Am, Bmat, bc, nullptr, nullptr, h1, NB, 128, 256, 1);
  dual_gemm<false><<<dim3(128, 1), blk, 0, stream>>>(h1, nullptr, nullptr,
      W2, nullptr, b2, nullptr, nullptr, h2, NB, 256, 128, 1);
  final_dot<<<2048, blk, 0, stream>>>(h2, W3, b3, out);

  (void)in_sizes; (void)n_in; (void)out_size; (void)ws_size;
}

// Round 2
// 739.087 us; speedup vs baseline: 6.3506x; 6.3506x over previous
//
#include <hip/hip_runtime.h>

namespace {

constexpr int HD  = 128;      // hidden dim
constexpr int NE  = 600000;   // edges per direction
constexpr int NDR = 200000;   // drugs
constexpr int NDI = 100000;   // diseases
constexpr int NB  = 8192;     // link batch

// ---------------- degree counts ----------------
__global__ void count_kernel(const int* __restrict__ dst, int n, int* __restrict__ cnt) {
  int i = blockIdx.x * 256 + threadIdx.x;
  if (i < n) atomicAdd(&cnt[dst[i]], 1);
}

// ---------------- 3-phase exclusive scan (chunk = 1024 elems/block) ----------------
__global__ void scan1(const int* __restrict__ in, int n, int* __restrict__ out,
                      int* __restrict__ bsum) {
  __shared__ int s[256];
  int t = threadIdx.x;
  int idx = blockIdx.x * 1024 + t * 4;
  int4 v = make_int4(0, 0, 0, 0);
  if (idx + 3 < n) {
    v = *reinterpret_cast<const int4*>(in + idx);
  } else {
    if (idx     < n) v.x = in[idx];
    if (idx + 1 < n) v.y = in[idx + 1];
    if (idx + 2 < n) v.z = in[idx + 2];
    if (idx + 3 < n) v.w = in[idx + 3];
  }
  int tsum = v.x + v.y + v.z + v.w;
  s[t] = tsum;
  __syncthreads();
  for (int o = 1; o < 256; o <<= 1) {
    int x = (t >= o) ? s[t - o] : 0;
    __syncthreads();
    s[t] += x;
    __syncthreads();
  }
  int excl = s[t] - tsum;
  if (idx     < n) out[idx]     = excl;
  if (idx + 1 < n) out[idx + 1] = excl + v.x;
  if (idx + 2 < n) out[idx + 2] = excl + v.x + v.y;
  if (idx + 3 < n) out[idx + 3] = excl + v.x + v.y + v.z;
  if (t == 255) bsum[blockIdx.x] = s[255];
}

__global__ void scan2(int* __restrict__ bsum, int nb) {
  __shared__ int s[256];
  int t = threadIdx.x;
  int v = (t < nb) ? bsum[t] : 0;
  s[t] = v;
  __syncthreads();
  for (int o = 1; o < 256; o <<= 1) {
    int x = (t >= o) ? s[t - o] : 0;
    __syncthreads();
    s[t] += x;
    __syncthreads();
  }
  if (t < nb) bsum[t] = s[t] - v;  // exclusive scan of block sums
}

__global__ void scan3(int* __restrict__ out, int n, const int* __restrict__ bsum) {
  int i = blockIdx.x * 256 + threadIdx.x;
  if (i < n) out[i] += bsum[i >> 10];
}

// ---------------- CSR bucket scatter: csr[off[dst]+k] = src ----------------
__global__ void csr_scatter(const int* __restrict__ src, const int* __restrict__ dst, int nE,
                            const int* __restrict__ off, int* __restrict__ cursor,
                            int* __restrict__ csr) {
  int e = blockIdx.x * 256 + threadIdx.x;
  if (e >= nE) return;
  int d = dst[e];
  int p = off[d] + atomicAdd(&cursor[d], 1);
  csr[p] = src[e];
}

// ---------------- mark demanded nodes: batch nodes + their in-neighbors ----------------
__global__ void mark_kernel(const int* __restrict__ drug_idx, const int* __restrict__ dis_idx,
                            const int* __restrict__ off_drug, const int* __restrict__ cnt_drug,
                            const int* __restrict__ csr_di2dr,
                            const int* __restrict__ off_dis, const int* __restrict__ cnt_dis,
                            const int* __restrict__ csr_d2di,
                            int* __restrict__ flag_drug, int* __restrict__ flag_dis) {
  int i = blockIdx.x * 256 + threadIdx.x;
  if (i < NB) {
    int g = drug_idx[i];
    flag_drug[g] = 1;
    int o = off_drug[g], n = cnt_drug[g];
    for (int j = 0; j < n; ++j) flag_dis[csr_di2dr[o + j]] = 1;   // disease srcs feeding batch drugs
  } else if (i < 2 * NB) {
    int g = dis_idx[i - NB];
    flag_dis[g] = 1;
    int o = off_dis[g], n = cnt_dis[g];
    for (int j = 0; j < n; ++j) flag_drug[csr_d2di[o + j]] = 1;   // drug srcs feeding batch diseases
  }
}

__global__ void compact_kernel(const int* __restrict__ flag, int n,
                               int* __restrict__ list, int* __restrict__ counter) {
  int i = blockIdx.x * 256 + threadIdx.x;
  if (i < n && flag[i]) {
    int p = atomicAdd(counter, 1);
    list[p] = i;
  }
}

// ---------------- gather-based mean aggregation: 32 lanes per row ----------------
// agg[out] = mean_{s in csr[off[g]..off[g]+cnt[g])} x[s]
__global__ void gather_agg(const float* __restrict__ x, const int* __restrict__ csr,
                           const int* __restrict__ off, const int* __restrict__ cnt,
                           const int* __restrict__ list, const int* __restrict__ nlistDev,
                           int nlistMax, int outByPos, float* __restrict__ agg) {
  int idx = blockIdx.x * 256 + threadIdx.x;
  int r = idx >> 5, c = idx & 31;
  int nl = nlistDev ? *nlistDev : nlistMax;
  if (r >= nl) return;
  int g = list ? list[r] : r;
  int o = off[g], n = cnt[g];
  float4 acc = make_float4(0.f, 0.f, 0.f, 0.f);
  for (int j = 0; j < n; ++j) {
    int s = csr[o + j];
    float4 v = reinterpret_cast<const float4*>(x + (size_t)s * HD)[c];
    acc.x += v.x; acc.y += v.y; acc.z += v.z; acc.w += v.w;
  }
  float inv = 1.0f / (float)max(n, 1);
  int orow = outByPos ? r : g;
  reinterpret_cast<float4*>(agg + (size_t)orow * HD)[c] =
      make_float4(acc.x * inv, acc.y * inv, acc.z * inv, acc.w * inv);
}

// ---------------- dual GEMM: Out = act(In1 @ Wa^T + In2 @ Wb^T + bias) ----------
// Tile: 64 rows x 128 cols per block (blockIdx.y = 128-col slab). 256 threads,
// each computes 4 rows x 8 cols. K-chunks of 32 staged in LDS.
// Row count may live on device (nRowsDev). map1/map2 gather input rows, omap
// scatters output rows. In-place Out==In1 is safe when map1==omap (each block
// reads only rows it writes, all writes after all reads).
template <bool DUAL>
__global__ __launch_bounds__(256) void dual_gemm(
    const float* __restrict__ In1, const float* __restrict__ In2,
    const float* __restrict__ Wa, const float* __restrict__ Wb,  // [J][K] row-major
    const float* __restrict__ bias,
    const int* __restrict__ map1, const int* __restrict__ map2,
    const int* __restrict__ omap, const int* __restrict__ nRowsDev,
    float* __restrict__ Out, int nRowsMax, int K, int Jtot, int relu) {
  __shared__ float sIn1[64][36];                  // [r][k]
  __shared__ float sIn2[DUAL ? 64 : 1][36];
  __shared__ float sWa[32][132];                  // [k][j]
  __shared__ float sWb[DUAL ? 32 : 1][132];

  const int nRows = nRowsDev ? *nRowsDev : nRowsMax;
  const int row0 = blockIdx.x * 64;
  if (row0 >= nRows) return;

  const int tid = threadIdx.x;
  const int colSlab = blockIdx.y * 128;
  const int tr = (tid >> 4) * 4;   // compute: 16 row-groups x 4 rows
  const int tc = (tid & 15) * 8;   //          16 col-groups x 8 cols
  const int lr = tid >> 2;         // staging In: 64 rows x (4 thr x 8 floats)
  const int lk = (tid & 3) * 4;
  const int wj = tid >> 1;         // staging W: 128 rows x (2 thr x 16 floats)
  const int wk = (tid & 1) * 16;

  int re = row0 + lr;
  if (re > nRows - 1) re = nRows - 1;
  const int g1 = map1 ? map1[re] : re;
  const int g2 = (DUAL && map2) ? map2[re] : re;

  float acc[4][8];
#pragma unroll
  for (int i = 0; i < 4; ++i)
#pragma unroll
    for (int j = 0; j < 8; ++j) acc[i][j] = bias[colSlab + tc + j];

  for (int kc = 0; kc < K; kc += 32) {
    {
      const float* p = In1 + (size_t)g1 * K + kc + lk;
      float4 v0 = *reinterpret_cast<const float4*>(p);
      float4 v1 = *reinterpret_cast<const float4*>(p + 16);
      sIn1[lr][lk + 0] = v0.x;  sIn1[lr][lk + 1] = v0.y;
      sIn1[lr][lk + 2] = v0.z;  sIn1[lr][lk + 3] = v0.w;
      sIn1[lr][lk + 16] = v1.x; sIn1[lr][lk + 17] = v1.y;
      sIn1[lr][lk + 18] = v1.z; sIn1[lr][lk + 19] = v1.w;
    }
    if (DUAL) {
      const float* p = In2 + (size_t)g2 * K + kc + lk;
      float4 v0 = *reinterpret_cast<const float4*>(p);
      float4 v1 = *reinterpret_cast<const float4*>(p + 16);
      sIn2[lr][lk + 0] = v0.x;  sIn2[lr][lk + 1] = v0.y;
      sIn2[lr][lk + 2] = v0.z;  sIn2[lr][lk + 3] = v0.w;
      sIn2[lr][lk + 16] = v1.x; sIn2[lr][lk + 17] = v1.y;
      sIn2[lr][lk + 18] = v1.z; sIn2[lr][lk + 19] = v1.w;
    }
    {
      const float* p = Wa + (size_t)(colSlab + wj) * K + kc + wk;
#pragma unroll
      for (int i = 0; i < 4; ++i) {
        float4 w = reinterpret_cast<const float4*>(p)[i];
        sWa[wk + i * 4 + 0][wj] = w.x;
        sWa[wk + i * 4 + 1][wj] = w.y;
        sWa[wk + i * 4 + 2][wj] = w.z;
        sWa[wk + i * 4 + 3][wj] = w.w;
      }
    }
    if (DUAL) {
      const float* p = Wb + (size_t)(colSlab + wj) * K + kc + wk;
#pragma unroll
      for (int i = 0; i < 4; ++i) {
        float4 w = reinterpret_cast<const float4*>(p)[i];
        sWb[wk + i * 4 + 0][wj] = w.x;
        sWb[wk + i * 4 + 1][wj] = w.y;
        sWb[wk + i * 4 + 2][wj] = w.z;
        sWb[wk + i * 4 + 3][wj] = w.w;
      }
    }
    __syncthreads();
#pragma unroll 4
    for (int k = 0; k < 32; ++k) {
      float a1[4];
#pragma unroll
      for (int i = 0; i < 4; ++i) a1[i] = sIn1[tr + i][k];
      float4 wa0 = *reinterpret_cast<const float4*>(&sWa[k][tc]);
      float4 wa1 = *reinterpret_cast<const float4*>(&sWa[k][tc + 4]);
      const float wav[8] = {wa0.x, wa0.y, wa0.z, wa0.w, wa1.x, wa1.y, wa1.z, wa1.w};
#pragma unroll
      for (int i = 0; i < 4; ++i)
#pragma unroll
        for (int j = 0; j < 8; ++j) acc[i][j] += a1[i] * wav[j];
      if (DUAL) {
        float a2[4];
#pragma unroll
        for (int i = 0; i < 4; ++i) a2[i] = sIn2[tr + i][k];
        float4 wb0 = *reinterpret_cast<const float4*>(&sWb[k][tc]);
        float4 wb1 = *reinterpret_cast<const float4*>(&sWb[k][tc + 4]);
        const float wbv[8] = {wb0.x, wb0.y, wb0.z, wb0.w, wb1.x, wb1.y, wb1.z, wb1.w};
#pragma unroll
        for (int i = 0; i < 4; ++i)
#pragma unroll
          for (int j = 0; j < 8; ++j) acc[i][j] += a2[i] * wbv[j];
      }
    }
    __syncthreads();
  }

  if (relu) {
#pragma unroll
    for (int i = 0; i < 4; ++i)
#pragma unroll
      for (int j = 0; j < 8; ++j) acc[i][j] = fmaxf(acc[i][j], 0.0f);
  }
#pragma unroll
  for (int i = 0; i < 4; ++i) {
    int r = row0 + tr + i;
    if (r < nRows) {
      int orow = omap ? omap[r] : r;
      float* po = Out + (size_t)orow * Jtot + colSlab + tc;
      *reinterpret_cast<float4*>(po)     = make_float4(acc[i][0], acc[i][1], acc[i][2], acc[i][3]);
      *reinterpret_cast<float4*>(po + 4) = make_float4(acc[i][4], acc[i][5], acc[i][6], acc[i][7]);
    }
  }
}

// ---------------- fold attention (len-1 softmax == identity): Wfold = Wout @ Wv ------
__global__ void fold_attn(const float* __restrict__ Win, const float* __restrict__ bin,
                          const float* __restrict__ Wout, const float* __restrict__ bout,
                          float* __restrict__ Wfold, float* __restrict__ bfold) {
  int s = blockIdx.x >> 7, m = blockIdx.x & 127, k = threadIdx.x;
  const float* wout_row = Wout + ((size_t)s * HD + m) * HD;        // Wout[s][m][:]
  const float* wv = Win + (size_t)s * 3 * HD * HD + 2 * HD * HD;   // Wv[s][:][:]
  float acc = 0.0f;
  for (int u = 0; u < HD; ++u) acc += wout_row[u] * wv[u * HD + k];
  Wfold[((size_t)s * HD + m) * HD + k] = acc;
  if (k == 0) {
    const float* bv = bin + (size_t)s * 3 * HD + 2 * HD;
    float b = bout[s * HD + m];
    for (int u = 0; u < HD; ++u) b += wout_row[u] * bv[u];
    bfold[s * HD + m] = b;
  }
}

// ---------------- fold attn into MLP layer 1 ----------------
// h1 = relu(drug_emb @ A^T + dis_emb @ B^T + bc)
__global__ void fold_mlp(const float* __restrict__ W1, const float* __restrict__ b1,
                         const float* __restrict__ Wfold, const float* __restrict__ bfold,
                         float* __restrict__ A, float* __restrict__ Bm, float* __restrict__ bc) {
  int r = blockIdx.x, k = threadIdx.x;
  const float* w1r = W1 + (size_t)r * 512;
  const float* Wf0 = Wfold;            // module 0: drug_att <- dis_emb
  const float* Wf1 = Wfold + HD * HD;  // module 1: dis_att  <- drug_emb
  float accA = 0.0f, accB = 0.0f;
  for (int m = 0; m < HD; ++m) {
    accA += w1r[384 + m] * Wf1[m * HD + k];
    accB += w1r[256 + m] * Wf0[m * HD + k];
  }
  A[(size_t)r * HD + k]  = w1r[k] + accA;
  Bm[(size_t)r * HD + k] = w1r[128 + k] + accB;
  if (k == 0) {
    float b = b1[r];
    for (int m = 0; m < HD; ++m) b += w1r[256 + m] * bfold[m] + w1r[384 + m] * bfold[HD + m];
    bc[r] = b;
  }
}

// ---------------- final dot: out[b] = h2[b] . W3 + b3 ----------------
__global__ void final_dot(const float* __restrict__ h2, const float* __restrict__ W3,
                          const float* __restrict__ b3, float* __restrict__ out) {
  int b = blockIdx.x * 4 + (threadIdx.x >> 6);
  int lane = threadIdx.x & 63;
  float2 hv = reinterpret_cast<const float2*>(h2 + (size_t)b * HD)[lane];
  float2 wv = reinterpret_cast<const float2*>(W3)[lane];
  float v = hv.x * wv.x + hv.y * wv.y;
  for (int off = 32; off; off >>= 1) v += __shfl_down(v, off);
  if (lane == 0) out[b] = v + b3[0];
}

}  // namespace

extern "C" void kernel_launch(void* const* d_in, const int* in_sizes, int n_in,
                              void* d_out, int out_size, void* d_ws, size_t ws_size,
                              hipStream_t stream) {
  const int* src_d2di  = (const int*)d_in[0];
  const int* dst_d2di  = (const int*)d_in[1];
  const int* src_di2dr = (const int*)d_in[2];
  const int* dst_di2dr = (const int*)d_in[3];
  const int* drug_idx  = (const int*)d_in[4];
  const int* dis_idx   = (const int*)d_in[5];
  const float* emb_drug = (const float*)d_in[6];
  const float* emb_dis  = (const float*)d_in[7];
  const float* Wl = (const float*)d_in[8];
  const float* bl = (const float*)d_in[9];
  const float* Wr = (const float*)d_in[10];
  const float* attn_Win  = (const float*)d_in[11];
  const float* attn_bin  = (const float*)d_in[12];
  const float* attn_Wout = (const float*)d_in[13];
  const float* attn_bout = (const float*)d_in[14];
  const float* W1 = (const float*)d_in[15];
  const float* b1 = (const float*)d_in[16];
  const float* W2 = (const float*)d_in[17];
  const float* b2 = (const float*)d_in[18];
  const float* W3 = (const float*)d_in[19];
  const float* b3 = (const float*)d_in[20];
  float* out = (float*)d_out;

  // ---- workspace carve ----
  float* ws = (float*)d_ws;
  size_t off = 0;
  auto carve = [&](size_t n) { float* p = ws + off; off += n; return p; };
  // zeroed int region (one memset): 3*(NDI+NDR)+8 ints
  int* cnt_dis     = (int*)carve(NDI);
  int* cnt_drug    = (int*)carve(NDR);
  int* cursor_dis  = (int*)carve(NDI);
  int* cursor_drug = (int*)carve(NDR);
  int* flag_dis    = (int*)carve(NDI);
  int* flag_drug   = (int*)carve(NDR);
  int* nctr        = (int*)carve(8);       // [0]=n_list_dis, [1]=n_list_drug
  const size_t zero_bytes = (3 * ((size_t)NDI + NDR) + 8) * 4;
  // not zeroed
  int* off_dis   = (int*)carve(NDI);
  int* off_drug  = (int*)carve(NDR);
  int* list_dis  = (int*)carve(NDI);
  int* list_drug = (int*)carve(NDR);
  int* csr_d2di  = (int*)carve(NE);        // srcs of in-edges, bucketed by disease dst
  int* csr_di2dr = (int*)carve(NE);        // srcs of in-edges, bucketed by drug dst
  int* bsum_dis  = (int*)carve(256);
  int* bsum_drug = (int*)carve(256);
  float* agg_dis  = carve((size_t)NDI * HD);   // L0 dis mean-agg; overwritten in-place by dis1_s0
  float* agg_drug = carve((size_t)NDR * HD);   // L0 drug mean-agg; overwritten in-place by drug1_s1
  float* drug1b    = carve((size_t)NB * HD);   // drug1 (stack0) at drug_idx rows
  float* dis1b     = carve((size_t)NB * HD);   // dis1 (stack1) at disease_idx rows
  float* aggB_drug = carve((size_t)NB * HD);   // L1 mean-agg at batch drug rows
  float* aggB_dis  = carve((size_t)NB * HD);   // L1 mean-agg at batch disease rows
  float* drug_emb  = carve((size_t)NB * HD);
  float* dis_emb   = carve((size_t)NB * HD);
  float* Wfold = carve(2 * HD * HD);
  float* bfold = carve(2 * HD);
  float* Am = carve(2 * HD * HD);
  float* Bmat = carve(2 * HD * HD);
  float* bc = carve(2 * HD);
  float* h1 = carve((size_t)NB * 2 * HD);
  float* h2 = carve((size_t)NB * HD);

  const size_t HH = (size_t)HD * HD;
  dim3 blk(256);

  hipMemsetAsync(cnt_dis, 0, zero_bytes, stream);

  // weight folding (independent of graph work)
  fold_attn<<<256, 128, 0, stream>>>(attn_Win, attn_bin, attn_Wout, attn_bout, Wfold, bfold);
  fold_mlp<<<256, 128, 0, stream>>>(W1, b1, Wfold, bfold, Am, Bmat, bc);

  // degree counts
  count_kernel<<<(NE + 255) / 256, blk, 0, stream>>>(dst_d2di, NE, cnt_dis);
  count_kernel<<<(NE + 255) / 256, blk, 0, stream>>>(dst_di2dr, NE, cnt_drug);

  // exclusive scans -> CSR row offsets
  scan1<<<(NDI + 1023) / 1024, blk, 0, stream>>>(cnt_dis, NDI, off_dis, bsum_dis);
  scan2<<<1, blk, 0, stream>>>(bsum_dis, (NDI + 1023) / 1024);
  scan3<<<(NDI + 255) / 256, blk, 0, stream>>>(off_dis, NDI, bsum_dis);
  scan1<<<(NDR + 1023) / 1024, blk, 0, stream>>>(cnt_drug, NDR, off_drug, bsum_drug);
  scan2<<<1, blk, 0, stream>>>(bsum_drug, (NDR + 1023) / 1024);
  scan3<<<(NDR + 255) / 256, blk, 0, stream>>>(off_drug, NDR, bsum_drug);

  // bucket srcs by destination
  csr_scatter<<<(NE + 255) / 256, blk, 0, stream>>>(src_d2di, dst_d2di, NE, off_dis, cursor_dis, csr_d2di);
  csr_scatter<<<(NE + 255) / 256, blk, 0, stream>>>(src_di2dr, dst_di2dr, NE, off_drug, cursor_drug, csr_di2dr);

  // demand set: batch nodes + their in-neighbors
  mark_kernel<<<(2 * NB + 255) / 256, blk, 0, stream>>>(drug_idx, dis_idx,
      off_drug, cnt_drug, csr_di2dr, off_dis, cnt_dis, csr_d2di, flag_drug, flag_dis);
  compact_kernel<<<(NDI + 255) / 256, blk, 0, stream>>>(flag_dis, NDI, list_dis, nctr + 0);
  compact_kernel<<<(NDR + 255) / 256, blk, 0, stream>>>(flag_drug, NDR, list_drug, nctr + 1);

  // layer-0 mean aggregation, demanded rows only (shared across stacks)
  gather_agg<<<(NDI * 32 + 255) / 256, blk, 0, stream>>>(emb_drug, csr_d2di, off_dis, cnt_dis,
      list_dis, nctr + 0, NDI, 0, agg_dis);
  gather_agg<<<(NDR * 32 + 255) / 256, blk, 0, stream>>>(emb_dis, csr_di2dr, off_drug, cnt_drug,
      list_drug, nctr + 1, NDR, 0, agg_drug);

  // layer-0 batch-row transforms (must precede in-place overwrites of agg buffers)
  // drug1b (stack0 at drug_idx, W[0][0][1] -> idx 1)
  dual_gemm<true><<<dim3(NB / 64, 1), blk, 0, stream>>>(agg_drug, emb_drug,
      Wl + 1 * HH, Wr + 1 * HH, bl + 1 * HD, drug_idx, drug_idx, nullptr, nullptr,
      drug1b, NB, 128, 128, 1);
  // dis1b (stack1 at disease_idx, W[1][0][0] -> idx 4)
  dual_gemm<true><<<dim3(NB / 64, 1), blk, 0, stream>>>(agg_dis, emb_dis,
      Wl + 4 * HH, Wr + 4 * HH, bl + 4 * HD, dis_idx, dis_idx, nullptr, nullptr,
      dis1b, NB, 128, 128, 1);

  // layer-0 demanded-row transforms, in-place over agg buffers
  // dis1_s0 at list_dis rows (W[0][0][0] -> idx 0)
  dual_gemm<true><<<dim3((NDI + 63) / 64, 1), blk, 0, stream>>>(agg_dis, emb_dis,
      Wl + 0 * HH, Wr + 0 * HH, bl + 0 * HD, list_dis, list_dis, list_dis, nctr + 0,
      agg_dis, NDI, 128, 128, 1);
  // drug1_s1 at list_drug rows (W[1][0][1] -> idx 5)
  dual_gemm<true><<<dim3((NDR + 63) / 64, 1), blk, 0, stream>>>(agg_drug, emb_drug,
      Wl + 5 * HH, Wr + 5 * HH, bl + 5 * HD, list_drug, list_drug, list_drug, nctr + 1,
      agg_drug, NDR, 128, 128, 1);

  // layer-1 mean aggregation, batch rows only (agg_dis now holds dis1_s0, agg_drug holds drug1_s1)
  gather_agg<<<(NB * 32) / 256, blk, 0, stream>>>(agg_dis, csr_di2dr, off_drug, cnt_drug,
      drug_idx, nullptr, NB, 1, aggB_drug);
  gather_agg<<<(NB * 32) / 256, blk, 0, stream>>>(agg_drug, csr_d2di, off_dis, cnt_dis,
      dis_idx, nullptr, NB, 1, aggB_dis);

  // layer-1 transforms at batch rows
  // drug_emb (W[0][1][1] -> idx 3)
  dual_gemm<true><<<dim3(NB / 64, 1), blk, 0, stream>>>(aggB_drug, drug1b,
      Wl + 3 * HH, Wr + 3 * HH, bl + 3 * HD, nullptr, nullptr, nullptr, nullptr,
      drug_emb, NB, 128, 128, 1);
  // dis_emb (W[1][1][0] -> idx 6)
  dual_gemm<true><<<dim3(NB / 64, 1), blk, 0, stream>>>(aggB_dis, dis1b,
      Wl + 6 * HH, Wr + 6 * HH, bl + 6 * HD, nullptr, nullptr, nullptr, nullptr,
      dis_emb, NB, 128, 128, 1);

  // link MLP (attention folded into Am/Bmat/bc)
  dual_gemm<true><<<dim3(NB / 64, 2), blk, 0, stream>>>(drug_emb, dis_emb,
      Am, Bmat, bc, nullptr, nullptr, nullptr, nullptr, h1, NB, 128, 256, 1);
  dual_gemm<false><<<dim3(NB / 64, 1), blk, 0, stream>>>(h1, nullptr,
      W2, nullptr, b2, nullptr, nullptr, nullptr, nullptr, h2, NB, 256, 128, 1);
  final_dot<<<NB / 4, blk, 0, stream>>>(h2, W3, b3, out);

  (void)in_sizes; (void)n_in; (void)out_size; (void)ws_size;
}

// Round 3
// 685.956 us; speedup vs baseline: 6.8425x; 1.0775x over previous
//
#include <hip/hip_runtime.h>

namespace {

constexpr int HD  = 128;      // hidden dim
constexpr int NE  = 600000;   // edges per direction
constexpr int NDR = 200000;   // drugs
constexpr int NDI = 100000;   // diseases
constexpr int NB  = 8192;     // link batch

typedef __attribute__((ext_vector_type(8))) short short8;   // 8 bf16 in 4 VGPRs
typedef __attribute__((ext_vector_type(4))) float f32x4;

// ---- split-bf16 helpers: x = hi + lo (truncated), ~16 mantissa bits total ----
__device__ inline void splitf(float x, unsigned short& h, unsigned short& l) {
  unsigned u = __float_as_uint(x);
  h = (unsigned short)(u >> 16);
  float r = x - __uint_as_float(u & 0xffff0000u);   // exact residual
  l = (unsigned short)(__float_as_uint(r) >> 16);
}
__device__ inline void split4(const float4& v, uint2& ph, uint2& pl) {
  unsigned ux = __float_as_uint(v.x), uy = __float_as_uint(v.y);
  unsigned uz = __float_as_uint(v.z), uw = __float_as_uint(v.w);
  ph.x = (ux >> 16) | (uy & 0xffff0000u);
  ph.y = (uz >> 16) | (uw & 0xffff0000u);
  float rx = v.x - __uint_as_float(ux & 0xffff0000u);
  float ry = v.y - __uint_as_float(uy & 0xffff0000u);
  float rz = v.z - __uint_as_float(uz & 0xffff0000u);
  float rw = v.w - __uint_as_float(uw & 0xffff0000u);
  pl.x = (__float_as_uint(rx) >> 16) | (__float_as_uint(ry) & 0xffff0000u);
  pl.y = (__float_as_uint(rz) >> 16) | (__float_as_uint(rw) & 0xffff0000u);
}

// ---------------- degree counts (both directions in one launch) ----------------
__global__ void count2(const int* __restrict__ d0, const int* __restrict__ d1, int n,
                       int* __restrict__ c0, int* __restrict__ c1) {
  int i = blockIdx.x * 256 + threadIdx.x;
  if (i >= n) return;
  if (blockIdx.y == 0) atomicAdd(&c0[d0[i]], 1);
  else                 atomicAdd(&c1[d1[i]], 1);
}

// ---------------- 3-phase exclusive scan, y selects dis/drug ----------------
__global__ void scan1y(const int* __restrict__ in0, int n0_, int* __restrict__ out0, int* __restrict__ bs0,
                       const int* __restrict__ in1, int n1_, int* __restrict__ out1, int* __restrict__ bs1) {
  const int* in; int n; int* outp; int* bs;
  if (blockIdx.y == 0) { in = in0; n = n0_; outp = out0; bs = bs0; }
  else                 { in = in1; n = n1_; outp = out1; bs = bs1; }
  if (blockIdx.x * 1024 >= n) return;
  __shared__ int s[256];
  int t = threadIdx.x;
  int idx = blockIdx.x * 1024 + t * 4;
  int4 v = make_int4(0, 0, 0, 0);
  if (idx + 3 < n) v = *reinterpret_cast<const int4*>(in + idx);
  else {
    if (idx     < n) v.x = in[idx];
    if (idx + 1 < n) v.y = in[idx + 1];
    if (idx + 2 < n) v.z = in[idx + 2];
    if (idx + 3 < n) v.w = in[idx + 3];
  }
  int tsum = v.x + v.y + v.z + v.w;
  s[t] = tsum;
  __syncthreads();
  for (int o = 1; o < 256; o <<= 1) {
    int x = (t >= o) ? s[t - o] : 0;
    __syncthreads();
    s[t] += x;
    __syncthreads();
  }
  int excl = s[t] - tsum;
  if (idx     < n) outp[idx]     = excl;
  if (idx + 1 < n) outp[idx + 1] = excl + v.x;
  if (idx + 2 < n) outp[idx + 2] = excl + v.x + v.y;
  if (idx + 3 < n) outp[idx + 3] = excl + v.x + v.y + v.z;
  if (t == 255) bs[blockIdx.x] = s[255];
}

__global__ void scan2(int* __restrict__ bs0, int nb0, int* __restrict__ bs1, int nb1) {
  int* bsum = (blockIdx.x == 0) ? bs0 : bs1;
  int nb = (blockIdx.x == 0) ? nb0 : nb1;
  __shared__ int s[256];
  int t = threadIdx.x;
  int v = (t < nb) ? bsum[t] : 0;
  s[t] = v;
  __syncthreads();
  for (int o = 1; o < 256; o <<= 1) {
    int x = (t >= o) ? s[t - o] : 0;
    __syncthreads();
    s[t] += x;
    __syncthreads();
  }
  if (t < nb) bsum[t] = s[t] - v;
}

__global__ void scan3y(int* __restrict__ out0, int n0_, const int* __restrict__ bs0,
                       int* __restrict__ out1, int n1_, const int* __restrict__ bs1) {
  int* outp; int n; const int* bs;
  if (blockIdx.y == 0) { outp = out0; n = n0_; bs = bs0; }
  else                 { outp = out1; n = n1_; bs = bs1; }
  int i = blockIdx.x * 256 + threadIdx.x;
  if (i < n) outp[i] += bs[i >> 10];
}

// ---------------- CSR bucket scatter (both directions) ----------------
__global__ void csr2(const int* __restrict__ s0, const int* __restrict__ d0,
                     const int* __restrict__ s1, const int* __restrict__ d1, int nE,
                     const int* __restrict__ off0, int* __restrict__ cur0, int* __restrict__ csr0,
                     const int* __restrict__ off1, int* __restrict__ cur1, int* __restrict__ csr1) {
  int e = blockIdx.x * 256 + threadIdx.x;
  if (e >= nE) return;
  if (blockIdx.y == 0) {
    int d = d0[e];
    csr0[off0[d] + atomicAdd(&cur0[d], 1)] = s0[e];
  } else {
    int d = d1[e];
    csr1[off1[d] + atomicAdd(&cur1[d], 1)] = s1[e];
  }
}

// ---------------- mark demanded nodes: batch nodes + their in-neighbors ----------------
__global__ void mark_kernel(const int* __restrict__ drug_idx, const int* __restrict__ dis_idx,
                            const int* __restrict__ off_drug, const int* __restrict__ cnt_drug,
                            const int* __restrict__ csr_di2dr,
                            const int* __restrict__ off_dis, const int* __restrict__ cnt_dis,
                            const int* __restrict__ csr_d2di,
                            int* __restrict__ flag_drug, int* __restrict__ flag_dis) {
  int i = blockIdx.x * 256 + threadIdx.x;
  if (i < NB) {
    int g = drug_idx[i];
    flag_drug[g] = 1;
    int o = off_drug[g], n = cnt_drug[g];
    for (int j = 0; j < n; ++j) flag_dis[csr_di2dr[o + j]] = 1;
  } else if (i < 2 * NB) {
    int g = dis_idx[i - NB];
    flag_dis[g] = 1;
    int o = off_dis[g], n = cnt_dis[g];
    for (int j = 0; j < n; ++j) flag_drug[csr_d2di[o + j]] = 1;
  }
}

// ---------------- compact flags -> list + pos (both sides) ----------------
__global__ void compact2(const int* __restrict__ f0, int n0_, int* __restrict__ l0,
                         int* __restrict__ p0, int* __restrict__ c0,
                         const int* __restrict__ f1, int n1_, int* __restrict__ l1,
                         int* __restrict__ p1, int* __restrict__ c1) {
  int i = blockIdx.x * 256 + threadIdx.x;
  if (blockIdx.y == 0) {
    if (i < n0_ && f0[i]) { int p = atomicAdd(c0, 1); l0[p] = i; p0[i] = p; }
  } else {
    if (i < n1_ && f1[i]) { int p = atomicAdd(c1, 1); l1[p] = i; p1[i] = p; }
  }
}

// ---------------- batch node -> list position ----------------
__global__ void batchpos_k(const int* __restrict__ drug_idx, const int* __restrict__ dis_idx,
                           const int* __restrict__ pos_drug, const int* __restrict__ pos_dis,
                           int* __restrict__ bp_drug, int* __restrict__ bp_dis) {
  int i = blockIdx.x * 256 + threadIdx.x;
  if (i < NB) bp_drug[i] = pos_drug[drug_idx[i]];
  else if (i < 2 * NB) { int j = i - NB; bp_dis[j] = pos_dis[dis_idx[j]]; }
}

// ---------------- L0 gather: f32 rows in, split-bf16 mean out at list position ----------------
__global__ void gather_f2s(const float* __restrict__ x, const int* __restrict__ csr,
                           const int* __restrict__ off, const int* __restrict__ cnt,
                           const int* __restrict__ list, const int* __restrict__ nlistDev,
                           unsigned short* __restrict__ oh, unsigned short* __restrict__ ol) {
  int idx = blockIdx.x * 256 + threadIdx.x;
  int r = idx >> 5, c = idx & 31;
  if (r >= *nlistDev) return;
  int g = list[r];
  int o = off[g], n = cnt[g];
  float4 acc = make_float4(0.f, 0.f, 0.f, 0.f);
  for (int j = 0; j < n; ++j) {
    int s = csr[o + j];
    float4 v = reinterpret_cast<const float4*>(x + (size_t)s * HD)[c];
    acc.x += v.x; acc.y += v.y; acc.z += v.z; acc.w += v.w;
  }
  float inv = 1.0f / (float)max(n, 1);
  float4 m = make_float4(acc.x * inv, acc.y * inv, acc.z * inv, acc.w * inv);
  uint2 ph, pl;
  split4(m, ph, pl);
  reinterpret_cast<uint2*>(oh + (size_t)r * HD)[c] = ph;
  reinterpret_cast<uint2*>(ol + (size_t)r * HD)[c] = pl;
}

// ---------------- L1 gather: split rows (pos-indexed) in, split mean out at batch row ----------------
__global__ void gather_s2s(const unsigned short* __restrict__ xh, const unsigned short* __restrict__ xl,
                           const int* __restrict__ csr, const int* __restrict__ off,
                           const int* __restrict__ cnt, const int* __restrict__ pos,
                           const int* __restrict__ bidx,
                           unsigned short* __restrict__ oh, unsigned short* __restrict__ ol) {
  int idx = blockIdx.x * 256 + threadIdx.x;
  int r = idx >> 5, c = idx & 31;
  if (r >= NB) return;
  int g = bidx[r];
  int o = off[g], n = cnt[g];
  float4 acc = make_float4(0.f, 0.f, 0.f, 0.f);
  for (int j = 0; j < n; ++j) {
    int p = pos[csr[o + j]];
    uint2 hh = reinterpret_cast<const uint2*>(xh + (size_t)p * HD)[c];
    uint2 ll = reinterpret_cast<const uint2*>(xl + (size_t)p * HD)[c];
    acc.x += __uint_as_float(hh.x << 16) + __uint_as_float(ll.x << 16);
    acc.y += __uint_as_float(hh.x & 0xffff0000u) + __uint_as_float(ll.x & 0xffff0000u);
    acc.z += __uint_as_float(hh.y << 16) + __uint_as_float(ll.y << 16);
    acc.w += __uint_as_float(hh.y & 0xffff0000u) + __uint_as_float(ll.y & 0xffff0000u);
  }
  float inv = 1.0f / (float)max(n, 1);
  float4 m = make_float4(acc.x * inv, acc.y * inv, acc.z * inv, acc.w * inv);
  uint2 ph, pl;
  split4(m, ph, pl);
  reinterpret_cast<uint2*>(oh + (size_t)r * HD)[c] = ph;
  reinterpret_cast<uint2*>(ol + (size_t)r * HD)[c] = pl;
}

// ---------------- split emb rows (at list positions, compact) ----------------
__global__ void emb_split(const float* __restrict__ x, const int* __restrict__ list,
                          const int* __restrict__ nDev,
                          unsigned short* __restrict__ oh, unsigned short* __restrict__ ol) {
  int idx = blockIdx.x * 256 + threadIdx.x;
  int r = idx >> 5, c = idx & 31;
  if (r >= *nDev) return;
  int g = list[r];
  float4 v = reinterpret_cast<const float4*>(x + (size_t)g * HD)[c];
  uint2 ph, pl;
  split4(v, ph, pl);
  reinterpret_cast<uint2*>(oh + (size_t)r * HD)[c] = ph;
  reinterpret_cast<uint2*>(ol + (size_t)r * HD)[c] = pl;
}

// ---------------- split static weights ----------------
__global__ void split_weights(const float* __restrict__ Wl, const float* __restrict__ Wr,
                              const float* __restrict__ W2,
                              unsigned short* __restrict__ WLh, unsigned short* __restrict__ WLl,
                              unsigned short* __restrict__ WRh, unsigned short* __restrict__ WRl,
                              unsigned short* __restrict__ W2h, unsigned short* __restrict__ W2l) {
  const int widx[6] = {0, 1, 3, 4, 5, 6};
  int i = blockIdx.x * 256 + threadIdx.x;
  if (i < 98304) {
    int m = i >> 14, e = i & 16383;
    splitf(Wl[(size_t)widx[m] * 16384 + e], WLh[i], WLl[i]);
    splitf(Wr[(size_t)widx[m] * 16384 + e], WRh[i], WRl[i]);
  } else if (i < 131072) {
    int j = i - 98304;
    splitf(W2[j], W2h[j], W2l[j]);
  }
}

// ---------------- MFMA dual GEMM, no LDS, split-bf16 operands ----------------
// Out[m][n] = act( X1[m] . Wa[n] + X2[m] . Wb[n] + bias[n] ), rows K-major.
// Block: 64 rows x 128 cols; wave w -> 32-col strip; fragments are direct 16B loads.
template <bool DUAL>
__global__ __launch_bounds__(256) void mfma_gemm(
    const unsigned short* __restrict__ X1h, const unsigned short* __restrict__ X1l,
    const unsigned short* __restrict__ X2h, const unsigned short* __restrict__ X2l,
    const unsigned short* __restrict__ Wah, const unsigned short* __restrict__ Wal,
    const unsigned short* __restrict__ Wbh, const unsigned short* __restrict__ Wbl,
    const float* __restrict__ bias,
    const int* __restrict__ map1, const int* __restrict__ map2,
    const int* __restrict__ nRowsDev,
    unsigned short* __restrict__ Oh, unsigned short* __restrict__ Ol,
    float* __restrict__ Of32,
    int nRowsMax, int K, int Jtot, int relu) {
  const int nRows = nRowsDev ? *nRowsDev : nRowsMax;
  const int row0 = blockIdx.x * 64;
  if (row0 >= nRows) return;
  const int lane = threadIdx.x & 63;
  const int wv = threadIdx.x >> 6;
  const int quad = lane >> 4, m16 = lane & 15;
  const int n0 = blockIdx.y * 128 + wv * 32;

  int g1[4], g2[4];
#pragma unroll
  for (int rt = 0; rt < 4; ++rt) {
    int r = row0 + rt * 16 + m16;
    if (r > nRows - 1) r = nRows - 1;
    g1[rt] = map1 ? map1[r] : r;
    g2[rt] = DUAL ? (map2 ? map2[r] : r) : 0;
  }

  f32x4 acc[4][2];
#pragma unroll
  for (int ct = 0; ct < 2; ++ct) {
    float b = bias[n0 + ct * 16 + m16];
    f32x4 bb = {b, b, b, b};
#pragma unroll
    for (int rt = 0; rt < 4; ++rt) acc[rt][ct] = bb;
  }

  for (int kc = 0; kc < K; kc += 32) {
    const int koff = kc + quad * 8;
    short8 bah[2], bal[2], bbh[2], bbl[2];
#pragma unroll
    for (int ct = 0; ct < 2; ++ct) {
      size_t wo = (size_t)(n0 + ct * 16 + m16) * K + koff;
      bah[ct] = *reinterpret_cast<const short8*>(Wah + wo);
      bal[ct] = *reinterpret_cast<const short8*>(Wal + wo);
      if (DUAL) {
        bbh[ct] = *reinterpret_cast<const short8*>(Wbh + wo);
        bbl[ct] = *reinterpret_cast<const short8*>(Wbl + wo);
      }
    }
#pragma unroll
    for (int rt = 0; rt < 4; ++rt) {
      size_t xo = (size_t)g1[rt] * K + koff;
      short8 a1h = *reinterpret_cast<const short8*>(X1h + xo);
      short8 a1l = *reinterpret_cast<const short8*>(X1l + xo);
#pragma unroll
      for (int ct = 0; ct < 2; ++ct) {
        acc[rt][ct] = __builtin_amdgcn_mfma_f32_16x16x32_bf16(a1h, bah[ct], acc[rt][ct], 0, 0, 0);
        acc[rt][ct] = __builtin_amdgcn_mfma_f32_16x16x32_bf16(a1h, bal[ct], acc[rt][ct], 0, 0, 0);
        acc[rt][ct] = __builtin_amdgcn_mfma_f32_16x16x32_bf16(a1l, bah[ct], acc[rt][ct], 0, 0, 0);
      }
      if (DUAL) {
        size_t yo = (size_t)g2[rt] * K + koff;
        short8 a2h = *reinterpret_cast<const short8*>(X2h + yo);
        short8 a2l = *reinterpret_cast<const short8*>(X2l + yo);
#pragma unroll
        for (int ct = 0; ct < 2; ++ct) {
          acc[rt][ct] = __builtin_amdgcn_mfma_f32_16x16x32_bf16(a2h, bbh[ct], acc[rt][ct], 0, 0, 0);
          acc[rt][ct] = __builtin_amdgcn_mfma_f32_16x16x32_bf16(a2h, bbl[ct], acc[rt][ct], 0, 0, 0);
          acc[rt][ct] = __builtin_amdgcn_mfma_f32_16x16x32_bf16(a2l, bbh[ct], acc[rt][ct], 0, 0, 0);
        }
      }
    }
  }

  // epilogue: D[m = quad*4+i (in tile)][n = lane&15 (in tile)]
#pragma unroll
  for (int rt = 0; rt < 4; ++rt) {
#pragma unroll
    for (int i = 0; i < 4; ++i) {
      int m = row0 + rt * 16 + quad * 4 + i;
      if (m < nRows) {
#pragma unroll
        for (int ct = 0; ct < 2; ++ct) {
          float v = acc[rt][ct][i];
          if (relu) v = fmaxf(v, 0.0f);
          size_t o = (size_t)m * Jtot + n0 + ct * 16 + m16;
          if (Of32) Of32[o] = v;
          if (Oh) {
            unsigned short h, l;
            splitf(v, h, l);
            Oh[o] = h; Ol[o] = l;
          }
        }
      }
    }
  }
}

// ---------------- fold attention (len-1 softmax == identity): Wfold = Wout @ Wv ------
__global__ void fold_attn(const float* __restrict__ Win, const float* __restrict__ bin,
                          const float* __restrict__ Wout, const float* __restrict__ bout,
                          float* __restrict__ Wfold, float* __restrict__ bfold) {
  int s = blockIdx.x >> 7, m = blockIdx.x & 127, k = threadIdx.x;
  const float* wout_row = Wout + ((size_t)s * HD + m) * HD;
  const float* wv = Win + (size_t)s * 3 * HD * HD + 2 * HD * HD;
  float acc = 0.0f;
  for (int u = 0; u < HD; ++u) acc += wout_row[u] * wv[u * HD + k];
  Wfold[((size_t)s * HD + m) * HD + k] = acc;
  if (k == 0) {
    const float* bv = bin + (size_t)s * 3 * HD + 2 * HD;
    float b = bout[s * HD + m];
    for (int u = 0; u < HD; ++u) b += wout_row[u] * bv[u];
    bfold[s * HD + m] = b;
  }
}

// ---------------- fold attn into MLP layer 1, emit split-bf16 A/B ----------------
__global__ void fold_mlp(const float* __restrict__ W1, const float* __restrict__ b1,
                         const float* __restrict__ Wfold, const float* __restrict__ bfold,
                         unsigned short* __restrict__ Ah, unsigned short* __restrict__ Al,
                         unsigned short* __restrict__ Bh, unsigned short* __restrict__ Bl,
                         float* __restrict__ bc) {
  int r = blockIdx.x, k = threadIdx.x;
  const float* w1r = W1 + (size_t)r * 512;
  const float* Wf0 = Wfold;            // module 0: drug_att <- dis_emb
  const float* Wf1 = Wfold + HD * HD;  // module 1: dis_att  <- drug_emb
  float accA = 0.0f, accB = 0.0f;
  for (int m = 0; m < HD; ++m) {
    accA += w1r[384 + m] * Wf1[m * HD + k];
    accB += w1r[256 + m] * Wf0[m * HD + k];
  }
  splitf(w1r[k] + accA, Ah[(size_t)r * HD + k], Al[(size_t)r * HD + k]);
  splitf(w1r[128 + k] + accB, Bh[(size_t)r * HD + k], Bl[(size_t)r * HD + k]);
  if (k == 0) {
    float b = b1[r];
    for (int m = 0; m < HD; ++m) b += w1r[256 + m] * bfold[m] + w1r[384 + m] * bfold[HD + m];
    bc[r] = b;
  }
}

// ---------------- final dot: out[b] = h2[b] . W3 + b3 ----------------
__global__ void final_dot(const float* __restrict__ h2, const float* __restrict__ W3,
                          const float* __restrict__ b3, float* __restrict__ out) {
  int b = blockIdx.x * 4 + (threadIdx.x >> 6);
  int lane = threadIdx.x & 63;
  float2 hv = reinterpret_cast<const float2*>(h2 + (size_t)b * HD)[lane];
  float2 wv = reinterpret_cast<const float2*>(W3)[lane];
  float v = hv.x * wv.x + hv.y * wv.y;
  for (int off = 32; off; off >>= 1) v += __shfl_down(v, off);
  if (lane == 0) out[b] = v + b3[0];
}

}  // namespace

extern "C" void kernel_launch(void* const* d_in, const int* in_sizes, int n_in,
                              void* d_out, int out_size, void* d_ws, size_t ws_size,
                              hipStream_t stream) {
  const int* src_d2di  = (const int*)d_in[0];
  const int* dst_d2di  = (const int*)d_in[1];
  const int* src_di2dr = (const int*)d_in[2];
  const int* dst_di2dr = (const int*)d_in[3];
  const int* drug_idx  = (const int*)d_in[4];
  const int* dis_idx   = (const int*)d_in[5];
  const float* emb_drug = (const float*)d_in[6];
  const float* emb_dis  = (const float*)d_in[7];
  const float* Wl = (const float*)d_in[8];
  const float* bl = (const float*)d_in[9];
  const float* Wr = (const float*)d_in[10];
  const float* attn_Win  = (const float*)d_in[11];
  const float* attn_bin  = (const float*)d_in[12];
  const float* attn_Wout = (const float*)d_in[13];
  const float* attn_bout = (const float*)d_in[14];
  const float* W1 = (const float*)d_in[15];
  const float* b1 = (const float*)d_in[16];
  const float* W2 = (const float*)d_in[17];
  const float* b2 = (const float*)d_in[18];
  const float* W3 = (const float*)d_in[19];
  const float* b3 = (const float*)d_in[20];
  float* out = (float*)d_out;

  // ---- workspace carve (16B-aligned float units) ----
  float* ws = (float*)d_ws;
  size_t off = 0;
  auto carve = [&](size_t nfloats) {
    float* p = ws + off;
    off += (nfloats + 3) & ~(size_t)3;
    return p;
  };
  auto carveU = [&](size_t nush) { return (unsigned short*)carve((nush + 1) / 2); };

  // zeroed int region (one memset)
  int* cnt_dis     = (int*)carve(NDI);
  int* cnt_drug    = (int*)carve(NDR);
  int* cursor_dis  = (int*)carve(NDI);
  int* cursor_drug = (int*)carve(NDR);
  int* flag_dis    = (int*)carve(NDI);
  int* flag_drug   = (int*)carve(NDR);
  int* nctr        = (int*)carve(8);       // [0]=n_list_dis, [1]=n_list_drug
  const size_t zero_bytes = (3 * ((size_t)NDI + NDR) + 8) * 4;
  // not zeroed
  int* off_dis   = (int*)carve(NDI);
  int* off_drug  = (int*)carve(NDR);
  int* list_dis  = (int*)carve(NDI);
  int* list_drug = (int*)carve(NDR);
  int* pos_dis   = (int*)carve(NDI);
  int* pos_drug  = (int*)carve(NDR);
  int* csr_d2di  = (int*)carve(NE);
  int* csr_di2dr = (int*)carve(NE);
  int* bsum_dis  = (int*)carve(256);
  int* bsum_drug = (int*)carve(256);
  int* bp_drug   = (int*)carve(NB);
  int* bp_dis    = (int*)carve(NB);

  // big split-bf16 buffers (compact, list-position indexed)
  unsigned short* aggh_dis  = carveU((size_t)NDI * HD);  // L0 agg -> overwritten in place by dis1_s0
  unsigned short* aggl_dis  = carveU((size_t)NDI * HD);
  unsigned short* aggh_drug = carveU((size_t)NDR * HD);  // L0 agg -> overwritten in place by drug1_s1
  unsigned short* aggl_drug = carveU((size_t)NDR * HD);
  unsigned short* embSh = carveU((size_t)NDR * HD);      // shared: dis rows first, then drug rows
  unsigned short* embSl = carveU((size_t)NDR * HD);
  // batch-sized split buffers
  unsigned short* d1bh = carveU((size_t)NB * HD);  // drug1 (stack0) at batch rows
  unsigned short* d1bl = carveU((size_t)NB * HD);
  unsigned short* s1bh = carveU((size_t)NB * HD);  // dis1 (stack1) at batch rows
  unsigned short* s1bl = carveU((size_t)NB * HD);
  unsigned short* aBdrh = carveU((size_t)NB * HD); // L1 agg at batch drug rows
  unsigned short* aBdrl = carveU((size_t)NB * HD);
  unsigned short* aBdih = carveU((size_t)NB * HD); // L1 agg at batch disease rows
  unsigned short* aBdil = carveU((size_t)NB * HD);
  unsigned short* deh = carveU((size_t)NB * HD);   // drug_emb split
  unsigned short* del = carveU((size_t)NB * HD);
  unsigned short* seh = carveU((size_t)NB * HD);   // dis_emb split
  unsigned short* sel = carveU((size_t)NB * HD);
  unsigned short* h1h = carveU((size_t)NB * 2 * HD);
  unsigned short* h1l = carveU((size_t)NB * 2 * HD);
  // weights (split)
  unsigned short* WLh = carveU(6 * 16384);
  unsigned short* WLl = carveU(6 * 16384);
  unsigned short* WRh = carveU(6 * 16384);
  unsigned short* WRl = carveU(6 * 16384);
  unsigned short* W2h = carveU(32768);
  unsigned short* W2l = carveU(32768);
  unsigned short* Amh = carveU(32768);
  unsigned short* Aml = carveU(32768);
  unsigned short* Bmh = carveU(32768);
  unsigned short* Bml = carveU(32768);
  // f32 small
  float* Wfold = carve(2 * HD * HD);
  float* bfold = carve(2 * HD);
  float* bc    = carve(2 * HD);
  float* h2    = carve((size_t)NB * HD);

  dim3 blk(256);
  const size_t WS = 16384;  // one 128x128 weight slot (elements)

  hipMemsetAsync(cnt_dis, 0, zero_bytes, stream);

  // weight prep (independent of graph work)
  fold_attn<<<256, 128, 0, stream>>>(attn_Win, attn_bin, attn_Wout, attn_bout, Wfold, bfold);
  fold_mlp<<<256, 128, 0, stream>>>(W1, b1, Wfold, bfold, Amh, Aml, Bmh, Bml, bc);
  split_weights<<<512, blk, 0, stream>>>(Wl, Wr, W2, WLh, WLl, WRh, WRl, W2h, W2l);

  // degree counts, scans, CSR
  count2<<<dim3((NE + 255) / 256, 2), blk, 0, stream>>>(dst_d2di, dst_di2dr, NE, cnt_dis, cnt_drug);
  scan1y<<<dim3((NDR + 1023) / 1024, 2), blk, 0, stream>>>(cnt_dis, NDI, off_dis, bsum_dis,
                                                           cnt_drug, NDR, off_drug, bsum_drug);
  scan2<<<2, blk, 0, stream>>>(bsum_dis, (NDI + 1023) / 1024, bsum_drug, (NDR + 1023) / 1024);
  scan3y<<<dim3((NDR + 255) / 256, 2), blk, 0, stream>>>(off_dis, NDI, bsum_dis, off_drug, NDR, bsum_drug);
  csr2<<<dim3((NE + 255) / 256, 2), blk, 0, stream>>>(src_d2di, dst_d2di, src_di2dr, dst_di2dr, NE,
                                                      off_dis, cursor_dis, csr_d2di,
                                                      off_drug, cursor_drug, csr_di2dr);

  // demand set + positions
  mark_kernel<<<(2 * NB + 255) / 256, blk, 0, stream>>>(drug_idx, dis_idx,
      off_drug, cnt_drug, csr_di2dr, off_dis, cnt_dis, csr_d2di, flag_drug, flag_dis);
  compact2<<<dim3((NDR + 255) / 256, 2), blk, 0, stream>>>(flag_dis, NDI, list_dis, pos_dis, nctr + 0,
                                                           flag_drug, NDR, list_drug, pos_drug, nctr + 1);
  batchpos_k<<<(2 * NB + 255) / 256, blk, 0, stream>>>(drug_idx, dis_idx, pos_drug, pos_dis, bp_drug, bp_dis);

  // layer-0 mean aggregation at list positions (shared across stacks)
  gather_f2s<<<(NDI * 32 + 255) / 256, blk, 0, stream>>>(emb_drug, csr_d2di, off_dis, cnt_dis,
      list_dis, nctr + 0, aggh_dis, aggl_dis);
  gather_f2s<<<(NDR * 32 + 255) / 256, blk, 0, stream>>>(emb_dis, csr_di2dr, off_drug, cnt_drug,
      list_drug, nctr + 1, aggh_drug, aggl_drug);

  // ---- disease-side L0 (uses embS as split emb_dis) ----
  emb_split<<<(NDI * 32 + 255) / 256, blk, 0, stream>>>(emb_dis, list_dis, nctr + 0, embSh, embSl);
  // dis1b (stack1 at batch diseases, W idx 4 -> slot 3)
  mfma_gemm<true><<<dim3(NB / 64, 1), blk, 0, stream>>>(
      aggh_dis, aggl_dis, embSh, embSl,
      WLh + 3 * WS, WLl + 3 * WS, WRh + 3 * WS, WRl + 3 * WS, bl + 4 * HD,
      bp_dis, bp_dis, nullptr, s1bh, s1bl, nullptr, NB, 128, 128, 1);
  // dis1_s0 at list rows (W idx 0 -> slot 0), in place over agg_dis
  mfma_gemm<true><<<dim3((NDI + 63) / 64, 1), blk, 0, stream>>>(
      aggh_dis, aggl_dis, embSh, embSl,
      WLh + 0 * WS, WLl + 0 * WS, WRh + 0 * WS, WRl + 0 * WS, bl + 0 * HD,
      nullptr, nullptr, nctr + 0, aggh_dis, aggl_dis, nullptr, NDI, 128, 128, 1);

  // ---- drug-side L0 (reuse embS for split emb_drug) ----
  emb_split<<<(NDR * 32 + 255) / 256, blk, 0, stream>>>(emb_drug, list_drug, nctr + 1, embSh, embSl);
  // drug1b (stack0 at batch drugs, W idx 1 -> slot 1)
  mfma_gemm<true><<<dim3(NB / 64, 1), blk, 0, stream>>>(
      aggh_drug, aggl_drug, embSh, embSl,
      WLh + 1 * WS, WLl + 1 * WS, WRh + 1 * WS, WRl + 1 * WS, bl + 1 * HD,
      bp_drug, bp_drug, nullptr, d1bh, d1bl, nullptr, NB, 128, 128, 1);
  // drug1_s1 at list rows (W idx 5 -> slot 4), in place over agg_drug
  mfma_gemm<true><<<dim3((NDR + 63) / 64, 1), blk, 0, stream>>>(
      aggh_drug, aggl_drug, embSh, embSl,
      WLh + 4 * WS, WLl + 4 * WS, WRh + 4 * WS, WRl + 4 * WS, bl + 5 * HD,
      nullptr, nullptr, nctr + 1, aggh_drug, aggl_drug, nullptr, NDR, 128, 128, 1);

  // layer-1 mean aggregation at batch rows (agg buffers now hold transformed L0 outputs)
  gather_s2s<<<(NB * 32) / 256, blk, 0, stream>>>(aggh_dis, aggl_dis, csr_di2dr, off_drug, cnt_drug,
      pos_dis, drug_idx, aBdrh, aBdrl);
  gather_s2s<<<(NB * 32) / 256, blk, 0, stream>>>(aggh_drug, aggl_drug, csr_d2di, off_dis, cnt_dis,
      pos_drug, dis_idx, aBdih, aBdil);

  // layer-1 transforms at batch rows
  // drug_emb (W idx 3 -> slot 2)
  mfma_gemm<true><<<dim3(NB / 64, 1), blk, 0, stream>>>(
      aBdrh, aBdrl, d1bh, d1bl,
      WLh + 2 * WS, WLl + 2 * WS, WRh + 2 * WS, WRl + 2 * WS, bl + 3 * HD,
      nullptr, nullptr, nullptr, deh, del, nullptr, NB, 128, 128, 1);
  // dis_emb (W idx 6 -> slot 5)
  mfma_gemm<true><<<dim3(NB / 64, 1), blk, 0, stream>>>(
      aBdih, aBdil, s1bh, s1bl,
      WLh + 5 * WS, WLl + 5 * WS, WRh + 5 * WS, WRl + 5 * WS, bl + 6 * HD,
      nullptr, nullptr, nullptr, seh, sel, nullptr, NB, 128, 128, 1);

  // link MLP (attention folded into Am/Bm/bc)
  mfma_gemm<true><<<dim3(NB / 64, 2), blk, 0, stream>>>(
      deh, del, seh, sel, Amh, Aml, Bmh, Bml, bc,
      nullptr, nullptr, nullptr, h1h, h1l, nullptr, NB, 128, 256, 1);
  mfma_gemm<false><<<dim3(NB / 64, 1), blk, 0, stream>>>(
      h1h, h1l, nullptr, nullptr, W2h, W2l, nullptr, nullptr, b2,
      nullptr, nullptr, nullptr, nullptr, nullptr, h2, NB, 256, 128, 1);
  final_dot<<<NB / 4, blk, 0, stream>>>(h2, W3, b3, out);

  (void)in_sizes; (void)n_in; (void)out_size; (void)ws_size;
}

// Round 5
// 570.673 us; speedup vs baseline: 8.2248x; 1.2020x over previous
//
#include <hip/hip_runtime.h>

namespace {

constexpr int HD  = 128;      // hidden dim
constexpr int NE  = 600000;   // edges per direction
constexpr int NDR = 200000;   // drugs
constexpr int NDI = 100000;   // diseases
constexpr int NB  = 8192;     // link batch

typedef __attribute__((ext_vector_type(8))) short short8;   // 8 bf16 in 4 VGPRs
typedef __attribute__((ext_vector_type(4))) float f32x4;

// ---- split-bf16 helpers: x = hi + lo (truncated), ~16 mantissa bits total ----
__device__ inline void splitf(float x, unsigned short& h, unsigned short& l) {
  unsigned u = __float_as_uint(x);
  h = (unsigned short)(u >> 16);
  float r = x - __uint_as_float(u & 0xffff0000u);   // exact residual
  l = (unsigned short)(__float_as_uint(r) >> 16);
}
__device__ inline void split4(const float4& v, uint2& ph, uint2& pl) {
  unsigned ux = __float_as_uint(v.x), uy = __float_as_uint(v.y);
  unsigned uz = __float_as_uint(v.z), uw = __float_as_uint(v.w);
  ph.x = (ux >> 16) | (uy & 0xffff0000u);
  ph.y = (uz >> 16) | (uw & 0xffff0000u);
  float rx = v.x - __uint_as_float(ux & 0xffff0000u);
  float ry = v.y - __uint_as_float(uy & 0xffff0000u);
  float rz = v.z - __uint_as_float(uz & 0xffff0000u);
  float rw = v.w - __uint_as_float(uw & 0xffff0000u);
  pl.x = (__float_as_uint(rx) >> 16) | (__float_as_uint(ry) & 0xffff0000u);
  pl.y = (__float_as_uint(rz) >> 16) | (__float_as_uint(rw) & 0xffff0000u);
}
// load 8 contiguous f32 and split into hi/lo bf16 fragments in-register
__device__ inline void split8(const float* p, short8& h8, short8& l8) {
  float4 v0 = *reinterpret_cast<const float4*>(p);
  float4 v1 = *reinterpret_cast<const float4*>(p + 4);
  uint2 h0, l0, h1, l1;
  split4(v0, h0, l0);
  split4(v1, h1, l1);
  union { unsigned u[4]; short8 s; } uh, ul;
  uh.u[0] = h0.x; uh.u[1] = h0.y; uh.u[2] = h1.x; uh.u[3] = h1.y;
  ul.u[0] = l0.x; ul.u[1] = l0.y; ul.u[2] = l1.x; ul.u[3] = l1.y;
  h8 = uh.s; l8 = ul.s;
}

// ---------------- batch flag + demand flag for batch nodes ----------------
__global__ void batch_mark(const int* __restrict__ drug_idx, const int* __restrict__ dis_idx,
                           int* __restrict__ fb_drug, int* __restrict__ fb_dis,
                           int* __restrict__ fd_drug, int* __restrict__ fd_dis) {
  int i = blockIdx.x * 256 + threadIdx.x;
  if (i < NB) { int g = drug_idx[i]; fb_drug[g] = 1; fd_drug[g] = 1; }
  else if (i < 2 * NB) { int g = dis_idx[i - NB]; fb_dis[g] = 1; fd_dis[g] = 1; }
}

// ---------------- edge-parallel demand mark: src of edges into batch dst ----------------
__global__ void edge_mark(const int* __restrict__ s0, const int* __restrict__ d0,   // d2di
                          const int* __restrict__ s1, const int* __restrict__ d1,   // di2dr
                          const int* __restrict__ fb_dis, const int* __restrict__ fb_drug,
                          int* __restrict__ fd_drug, int* __restrict__ fd_dis) {
  int e = blockIdx.x * 256 + threadIdx.x;
  if (e >= NE) return;
  if (blockIdx.y == 0) { if (fb_dis[d0[e]]) fd_drug[s0[e]] = 1; }
  else                 { if (fb_drug[d1[e]]) fd_dis[s1[e]] = 1; }
}

// ---------------- filtered degree counts (demanded dst only) ----------------
__global__ void count_f(const int* __restrict__ d0, const int* __restrict__ d1,
                        const int* __restrict__ fd_dis, const int* __restrict__ fd_drug,
                        int* __restrict__ c0, int* __restrict__ c1) {
  int e = blockIdx.x * 256 + threadIdx.x;
  if (e >= NE) return;
  if (blockIdx.y == 0) { int d = d0[e]; if (fd_dis[d]) atomicAdd(&c0[d], 1); }
  else                 { int d = d1[e]; if (fd_drug[d]) atomicAdd(&c1[d], 1); }
}

// ---------------- 3-phase exclusive scan, y selects dis/drug ----------------
__global__ void scan1y(const int* __restrict__ in0, int n0_, int* __restrict__ out0, int* __restrict__ bs0,
                       const int* __restrict__ in1, int n1_, int* __restrict__ out1, int* __restrict__ bs1) {
  const int* in; int n; int* outp; int* bs;
  if (blockIdx.y == 0) { in = in0; n = n0_; outp = out0; bs = bs0; }
  else                 { in = in1; n = n1_; outp = out1; bs = bs1; }
  if (blockIdx.x * 1024 >= n) return;
  __shared__ int s[256];
  int t = threadIdx.x;
  int idx = blockIdx.x * 1024 + t * 4;
  int4 v = make_int4(0, 0, 0, 0);
  if (idx + 3 < n) v = *reinterpret_cast<const int4*>(in + idx);
  else {
    if (idx     < n) v.x = in[idx];
    if (idx + 1 < n) v.y = in[idx + 1];
    if (idx + 2 < n) v.z = in[idx + 2];
    if (idx + 3 < n) v.w = in[idx + 3];
  }
  int tsum = v.x + v.y + v.z + v.w;
  s[t] = tsum;
  __syncthreads();
  for (int o = 1; o < 256; o <<= 1) {
    int x = (t >= o) ? s[t - o] : 0;
    __syncthreads();
    s[t] += x;
    __syncthreads();
  }
  int excl = s[t] - tsum;
  if (idx     < n) outp[idx]     = excl;
  if (idx + 1 < n) outp[idx + 1] = excl + v.x;
  if (idx + 2 < n) outp[idx + 2] = excl + v.x + v.y;
  if (idx + 3 < n) outp[idx + 3] = excl + v.x + v.y + v.z;
  if (t == 255) bs[blockIdx.x] = s[255];
}

__global__ void scan2(int* __restrict__ bs0, int nb0, int* __restrict__ bs1, int nb1) {
  int* bsum = (blockIdx.x == 0) ? bs0 : bs1;
  int nb = (blockIdx.x == 0) ? nb0 : nb1;
  __shared__ int s[256];
  int t = threadIdx.x;
  int v = (t < nb) ? bsum[t] : 0;
  s[t] = v;
  __syncthreads();
  for (int o = 1; o < 256; o <<= 1) {
    int x = (t >= o) ? s[t - o] : 0;
    __syncthreads();
    s[t] += x;
    __syncthreads();
  }
  if (t < nb) bsum[t] = s[t] - v;
}

__global__ void scan3y(int* __restrict__ out0, int n0_, const int* __restrict__ bs0,
                       int* __restrict__ out1, int n1_, const int* __restrict__ bs1) {
  int* outp; int n; const int* bs;
  if (blockIdx.y == 0) { outp = out0; n = n0_; bs = bs0; }
  else                 { outp = out1; n = n1_; bs = bs1; }
  int i = blockIdx.x * 256 + threadIdx.x;
  if (i < n) outp[i] += bs[i >> 10];
}

// ---------------- filtered CSR bucket scatter ----------------
__global__ void csr_f(const int* __restrict__ s0, const int* __restrict__ d0,
                      const int* __restrict__ s1, const int* __restrict__ d1, int nE,
                      const int* __restrict__ fd_dis, const int* __restrict__ fd_drug,
                      const int* __restrict__ off0, int* __restrict__ cur0, int* __restrict__ csr0,
                      const int* __restrict__ off1, int* __restrict__ cur1, int* __restrict__ csr1) {
  int e = blockIdx.x * 256 + threadIdx.x;
  if (e >= nE) return;
  if (blockIdx.y == 0) {
    int d = d0[e];
    if (fd_dis[d]) csr0[off0[d] + atomicAdd(&cur0[d], 1)] = s0[e];
  } else {
    int d = d1[e];
    if (fd_drug[d]) csr1[off1[d] + atomicAdd(&cur1[d], 1)] = s1[e];
  }
}

// ---------------- compact flags -> list + pos (both sides) ----------------
__global__ void compact2(const int* __restrict__ f0, int n0_, int* __restrict__ l0,
                         int* __restrict__ p0, int* __restrict__ c0,
                         const int* __restrict__ f1, int n1_, int* __restrict__ l1,
                         int* __restrict__ p1, int* __restrict__ c1) {
  int i = blockIdx.x * 256 + threadIdx.x;
  if (blockIdx.y == 0) {
    if (i < n0_ && f0[i]) { int p = atomicAdd(c0, 1); l0[p] = i; p0[i] = p; }
  } else {
    if (i < n1_ && f1[i]) { int p = atomicAdd(c1, 1); l1[p] = i; p1[i] = p; }
  }
}

// ---------------- batch node -> list position ----------------
__global__ void batchpos_k(const int* __restrict__ drug_idx, const int* __restrict__ dis_idx,
                           const int* __restrict__ pos_drug, const int* __restrict__ pos_dis,
                           int* __restrict__ bp_drug, int* __restrict__ bp_dis) {
  int i = blockIdx.x * 256 + threadIdx.x;
  if (i < NB) bp_drug[i] = pos_drug[drug_idx[i]];
  else if (i < 2 * NB) { int j = i - NB; bp_dis[j] = pos_dis[dis_idx[j]]; }
}

// ---------------- L0 gather (paired, y=direction): f32 in, split mean out at list pos ----------------
__global__ void gather_f2s(const float* __restrict__ x0, const int* __restrict__ csr0,
                           const int* __restrict__ off0, const int* __restrict__ cnt0,
                           const int* __restrict__ list0, const int* __restrict__ n0Dev,
                           unsigned short* __restrict__ oh0, unsigned short* __restrict__ ol0,
                           const float* __restrict__ x1, const int* __restrict__ csr1,
                           const int* __restrict__ off1, const int* __restrict__ cnt1,
                           const int* __restrict__ list1, const int* __restrict__ n1Dev,
                           unsigned short* __restrict__ oh1, unsigned short* __restrict__ ol1) {
  const float* x; const int *csr, *offp, *cnt, *list, *nDev;
  unsigned short *oh, *ol;
  if (blockIdx.y == 0) { x = x0; csr = csr0; offp = off0; cnt = cnt0; list = list0; nDev = n0Dev; oh = oh0; ol = ol0; }
  else                 { x = x1; csr = csr1; offp = off1; cnt = cnt1; list = list1; nDev = n1Dev; oh = oh1; ol = ol1; }
  int idx = blockIdx.x * 256 + threadIdx.x;
  int r = idx >> 5, c = idx & 31;
  if (r >= *nDev) return;
  int g = list[r];
  int o = offp[g], n = cnt[g];
  float4 acc = make_float4(0.f, 0.f, 0.f, 0.f);
  for (int j = 0; j < n; ++j) {
    int s = csr[o + j];
    float4 v = reinterpret_cast<const float4*>(x + (size_t)s * HD)[c];
    acc.x += v.x; acc.y += v.y; acc.z += v.z; acc.w += v.w;
  }
  float inv = 1.0f / (float)max(n, 1);
  float4 m = make_float4(acc.x * inv, acc.y * inv, acc.z * inv, acc.w * inv);
  uint2 ph, pl;
  split4(m, ph, pl);
  reinterpret_cast<uint2*>(oh + (size_t)r * HD)[c] = ph;
  reinterpret_cast<uint2*>(ol + (size_t)r * HD)[c] = pl;
}

// ---------------- L1 gather (paired): split rows (pos-indexed) in, split mean out at batch row ----
__global__ void gather_s2s(const unsigned short* __restrict__ xh0, const unsigned short* __restrict__ xl0,
                           const int* __restrict__ csr0, const int* __restrict__ off0,
                           const int* __restrict__ cnt0, const int* __restrict__ pos0,
                           const int* __restrict__ bidx0,
                           unsigned short* __restrict__ oh0, unsigned short* __restrict__ ol0,
                           const unsigned short* __restrict__ xh1, const unsigned short* __restrict__ xl1,
                           const int* __restrict__ csr1, const int* __restrict__ off1,
                           const int* __restrict__ cnt1, const int* __restrict__ pos1,
                           const int* __restrict__ bidx1,
                           unsigned short* __restrict__ oh1, unsigned short* __restrict__ ol1) {
  const unsigned short *xh, *xl; const int *csr, *offp, *cnt, *pos, *bidx;
  unsigned short *oh, *ol;
  if (blockIdx.y == 0) { xh = xh0; xl = xl0; csr = csr0; offp = off0; cnt = cnt0; pos = pos0; bidx = bidx0; oh = oh0; ol = ol0; }
  else                 { xh = xh1; xl = xl1; csr = csr1; offp = off1; cnt = cnt1; pos = pos1; bidx = bidx1; oh = oh1; ol = ol1; }
  int idx = blockIdx.x * 256 + threadIdx.x;
  int r = idx >> 5, c = idx & 31;
  if (r >= NB) return;
  int g = bidx[r];
  int o = offp[g], n = cnt[g];
  float4 acc = make_float4(0.f, 0.f, 0.f, 0.f);
  for (int j = 0; j < n; ++j) {
    int p = pos[csr[o + j]];
    uint2 hh = reinterpret_cast<const uint2*>(xh + (size_t)p * HD)[c];
    uint2 ll = reinterpret_cast<const uint2*>(xl + (size_t)p * HD)[c];
    acc.x += __uint_as_float(hh.x << 16) + __uint_as_float(ll.x << 16);
    acc.y += __uint_as_float(hh.x & 0xffff0000u) + __uint_as_float(ll.x & 0xffff0000u);
    acc.z += __uint_as_float(hh.y << 16) + __uint_as_float(ll.y << 16);
    acc.w += __uint_as_float(hh.y & 0xffff0000u) + __uint_as_float(ll.y & 0xffff0000u);
  }
  float inv = 1.0f / (float)max(n, 1);
  float4 m = make_float4(acc.x * inv, acc.y * inv, acc.z * inv, acc.w * inv);
  uint2 ph, pl;
  split4(m, ph, pl);
  reinterpret_cast<uint2*>(oh + (size_t)r * HD)[c] = ph;
  reinterpret_cast<uint2*>(ol + (size_t)r * HD)[c] = pl;
}

// ---------------- split static weights ----------------
__global__ void split_weights(const float* __restrict__ Wl, const float* __restrict__ Wr,
                              const float* __restrict__ W2,
                              unsigned short* __restrict__ WLh, unsigned short* __restrict__ WLl,
                              unsigned short* __restrict__ WRh, unsigned short* __restrict__ WRl,
                              unsigned short* __restrict__ W2h, unsigned short* __restrict__ W2l) {
  const int widx[6] = {0, 1, 3, 4, 5, 6};
  int i = blockIdx.x * 256 + threadIdx.x;
  if (i < 98304) {
    int m = i >> 14, e = i & 16383;
    splitf(Wl[(size_t)widx[m] * 16384 + e], WLh[i], WLl[i]);
    splitf(Wr[(size_t)widx[m] * 16384 + e], WRh[i], WRl[i]);
  } else if (i < 131072) {
    int j = i - 98304;
    splitf(W2[j], W2h[j], W2l[j]);
  }
}

// ---------------- MFMA dual GEMM (pairable), no LDS, split-bf16 operands ----------------
struct GemmArgs {
  const unsigned short* X1h; const unsigned short* X1l;
  const unsigned short* X2h; const unsigned short* X2l;  // used when x2f32 == nullptr
  const float* x2f32;                                    // f32 X2 with in-register split
  const unsigned short* Wah; const unsigned short* Wal;
  const unsigned short* Wbh; const unsigned short* Wbl;
  const float* bias;
  const int* map1; const int* map2;
  const int* nRowsDev;
  unsigned short* Oh; unsigned short* Ol;
  float* Of32;
  int nRowsMax; int K; int Jtot; int relu;
};

template <bool DUAL>
__device__ inline void gemm_body(const GemmArgs& A, int bx, int by, int tid) {
  const int nRows = A.nRowsDev ? *A.nRowsDev : A.nRowsMax;
  const int row0 = bx * 64;
  if (row0 >= nRows) return;
  const int colSlab = by * 128;
  if (colSlab >= A.Jtot) return;
  const int lane = tid & 63;
  const int wv = tid >> 6;
  const int quad = lane >> 4, m16 = lane & 15;
  const int n0 = colSlab + wv * 32;
  const int K = A.K;

  int g1[4], g2[4];
#pragma unroll
  for (int rt = 0; rt < 4; ++rt) {
    int r = row0 + rt * 16 + m16;
    if (r > nRows - 1) r = nRows - 1;
    g1[rt] = A.map1 ? A.map1[r] : r;
    g2[rt] = DUAL ? (A.map2 ? A.map2[r] : r) : 0;
  }

  f32x4 acc[4][2];
#pragma unroll
  for (int ct = 0; ct < 2; ++ct) {
    float b = A.bias[n0 + ct * 16 + m16];
    f32x4 bb = {b, b, b, b};
#pragma unroll
    for (int rt = 0; rt < 4; ++rt) acc[rt][ct] = bb;
  }

  for (int kc = 0; kc < K; kc += 32) {
    const int koff = kc + quad * 8;
    short8 bah[2], bal[2], bbh[2], bbl[2];
#pragma unroll
    for (int ct = 0; ct < 2; ++ct) {
      size_t wo = (size_t)(n0 + ct * 16 + m16) * K + koff;
      bah[ct] = *reinterpret_cast<const short8*>(A.Wah + wo);
      bal[ct] = *reinterpret_cast<const short8*>(A.Wal + wo);
      if (DUAL) {
        bbh[ct] = *reinterpret_cast<const short8*>(A.Wbh + wo);
        bbl[ct] = *reinterpret_cast<const short8*>(A.Wbl + wo);
      }
    }
#pragma unroll
    for (int rt = 0; rt < 4; ++rt) {
      size_t xo = (size_t)g1[rt] * K + koff;
      short8 a1h = *reinterpret_cast<const short8*>(A.X1h + xo);
      short8 a1l = *reinterpret_cast<const short8*>(A.X1l + xo);
#pragma unroll
      for (int ct = 0; ct < 2; ++ct) {
        acc[rt][ct] = __builtin_amdgcn_mfma_f32_16x16x32_bf16(a1h, bah[ct], acc[rt][ct], 0, 0, 0);
        acc[rt][ct] = __builtin_amdgcn_mfma_f32_16x16x32_bf16(a1h, bal[ct], acc[rt][ct], 0, 0, 0);
        acc[rt][ct] = __builtin_amdgcn_mfma_f32_16x16x32_bf16(a1l, bah[ct], acc[rt][ct], 0, 0, 0);
      }
      if (DUAL) {
        short8 a2h, a2l;
        if (A.x2f32) {
          split8(A.x2f32 + (size_t)g2[rt] * K + koff, a2h, a2l);
        } else {
          size_t yo = (size_t)g2[rt] * K + koff;
          a2h = *reinterpret_cast<const short8*>(A.X2h + yo);
          a2l = *reinterpret_cast<const short8*>(A.X2l + yo);
        }
#pragma unroll
        for (int ct = 0; ct < 2; ++ct) {
          acc[rt][ct] = __builtin_amdgcn_mfma_f32_16x16x32_bf16(a2h, bbh[ct], acc[rt][ct], 0, 0, 0);
          acc[rt][ct] = __builtin_amdgcn_mfma_f32_16x16x32_bf16(a2h, bbl[ct], acc[rt][ct], 0, 0, 0);
          acc[rt][ct] = __builtin_amdgcn_mfma_f32_16x16x32_bf16(a2l, bbh[ct], acc[rt][ct], 0, 0, 0);
        }
      }
    }
  }

  // epilogue: D[m = quad*4+i][n = m16] per 16x16 tile
#pragma unroll
  for (int rt = 0; rt < 4; ++rt) {
#pragma unroll
    for (int i = 0; i < 4; ++i) {
      int m = row0 + rt * 16 + quad * 4 + i;
      if (m < nRows) {
#pragma unroll
        for (int ct = 0; ct < 2; ++ct) {
          float v = acc[rt][ct][i];
          if (A.relu) v = fmaxf(v, 0.0f);
          size_t o = (size_t)m * A.Jtot + n0 + ct * 16 + m16;
          if (A.Of32) A.Of32[o] = v;
          if (A.Oh) {
            unsigned short h, l;
            splitf(v, h, l);
            A.Oh[o] = h; A.Ol[o] = l;
          }
        }
      }
    }
  }
}

template <bool DUAL>
__global__ __launch_bounds__(256) void mfma_pair(GemmArgs a, GemmArgs b, int agx) {
  int bx = blockIdx.x;
  if (bx < agx) gemm_body<DUAL>(a, bx, blockIdx.y, threadIdx.x);
  else          gemm_body<DUAL>(b, bx - agx, blockIdx.y, threadIdx.x);
}

// ---------------- fold attention (len-1 softmax == identity): Wfold = Wout @ Wv ------
__global__ void fold_attn(const float* __restrict__ Win, const float* __restrict__ bin,
                          const float* __restrict__ Wout, const float* __restrict__ bout,
                          float* __restrict__ Wfold, float* __restrict__ bfold) {
  int s = blockIdx.x >> 7, m = blockIdx.x & 127, k = threadIdx.x;
  const float* wout_row = Wout + ((size_t)s * HD + m) * HD;
  const float* wv = Win + (size_t)s * 3 * HD * HD + 2 * HD * HD;
  float acc = 0.0f;
  for (int u = 0; u < HD; ++u) acc += wout_row[u] * wv[u * HD + k];
  Wfold[((size_t)s * HD + m) * HD + k] = acc;
  if (k == 0) {
    const float* bv = bin + (size_t)s * 3 * HD + 2 * HD;
    float b = bout[s * HD + m];
    for (int u = 0; u < HD; ++u) b += wout_row[u] * bv[u];
    bfold[s * HD + m] = b;
  }
}

// ---------------- fold attn into MLP layer 1, emit split-bf16 A/B ----------------
__global__ void fold_mlp(const float* __restrict__ W1, const float* __restrict__ b1,
                         const float* __restrict__ Wfold, const float* __restrict__ bfold,
                         unsigned short* __restrict__ Ah, unsigned short* __restrict__ Al,
                         unsigned short* __restrict__ Bh, unsigned short* __restrict__ Bl,
                         float* __restrict__ bc) {
  int r = blockIdx.x, k = threadIdx.x;
  const float* w1r = W1 + (size_t)r * 512;
  const float* Wf0 = Wfold;            // module 0: drug_att <- dis_emb
  const float* Wf1 = Wfold + HD * HD;  // module 1: dis_att  <- drug_emb
  float accA = 0.0f, accB = 0.0f;
  for (int m = 0; m < HD; ++m) {
    accA += w1r[384 + m] * Wf1[m * HD + k];
    accB += w1r[256 + m] * Wf0[m * HD + k];
  }
  splitf(w1r[k] + accA, Ah[(size_t)r * HD + k], Al[(size_t)r * HD + k]);
  splitf(w1r[128 + k] + accB, Bh[(size_t)r * HD + k], Bl[(size_t)r * HD + k]);
  if (k == 0) {
    float b = b1[r];
    for (int m = 0; m < HD; ++m) b += w1r[256 + m] * bfold[m] + w1r[384 + m] * bfold[HD + m];
    bc[r] = b;
  }
}

// ---------------- final dot: out[b] = h2[b] . W3 + b3 ----------------
__global__ void final_dot(const float* __restrict__ h2, const float* __restrict__ W3,
                          const float* __restrict__ b3, float* __restrict__ out) {
  int b = blockIdx.x * 4 + (threadIdx.x >> 6);
  int lane = threadIdx.x & 63;
  float2 hv = reinterpret_cast<const float2*>(h2 + (size_t)b * HD)[lane];
  float2 wv = reinterpret_cast<const float2*>(W3)[lane];
  float v = hv.x * wv.x + hv.y * wv.y;
  for (int off = 32; off; off >>= 1) v += __shfl_down(v, off);
  if (lane == 0) out[b] = v + b3[0];
}

}  // namespace

extern "C" void kernel_launch(void* const* d_in, const int* in_sizes, int n_in,
                              void* d_out, int out_size, void* d_ws, size_t ws_size,
                              hipStream_t stream) {
  const int* src_d2di  = (const int*)d_in[0];
  const int* dst_d2di  = (const int*)d_in[1];
  const int* src_di2dr = (const int*)d_in[2];
  const int* dst_di2dr = (const int*)d_in[3];
  const int* drug_idx  = (const int*)d_in[4];
  const int* dis_idx   = (const int*)d_in[5];
  const float* emb_drug = (const float*)d_in[6];
  const float* emb_dis  = (const float*)d_in[7];
  const float* Wl = (const float*)d_in[8];
  const float* bl = (const float*)d_in[9];
  const float* Wr = (const float*)d_in[10];
  const float* attn_Win  = (const float*)d_in[11];
  const float* attn_bin  = (const float*)d_in[12];
  const float* attn_Wout = (const float*)d_in[13];
  const float* attn_bout = (const float*)d_in[14];
  const float* W1 = (const float*)d_in[15];
  const float* b1 = (const float*)d_in[16];
  const float* W2 = (const float*)d_in[17];
  const float* b2 = (const float*)d_in[18];
  const float* W3 = (const float*)d_in[19];
  const float* b3 = (const float*)d_in[20];
  float* out = (float*)d_out;

  // ---- workspace carve (16B-aligned float units) ----
  float* ws = (float*)d_ws;
  size_t off = 0;
  auto carve = [&](size_t nfloats) {
    float* p = ws + off;
    off += (nfloats + 3) & ~(size_t)3;
    return p;
  };
  auto carveU = [&](size_t nush) { return (unsigned short*)carve((nush + 1) / 2); };

  // zeroed int region (one memset)
  int* cnt_dis     = (int*)carve(NDI);
  int* cnt_drug    = (int*)carve(NDR);
  int* cursor_dis  = (int*)carve(NDI);
  int* cursor_drug = (int*)carve(NDR);
  int* fb_dis      = (int*)carve(NDI);
  int* fb_drug     = (int*)carve(NDR);
  int* fd_dis      = (int*)carve(NDI);
  int* fd_drug     = (int*)carve(NDR);
  int* nctr        = (int*)carve(8);       // [0]=n_list_dis, [1]=n_list_drug
  const size_t zero_bytes = (4 * ((size_t)NDI + NDR) + 8) * 4;
  // not zeroed
  int* off_dis   = (int*)carve(NDI);
  int* off_drug  = (int*)carve(NDR);
  int* list_dis  = (int*)carve(NDI);
  int* list_drug = (int*)carve(NDR);
  int* pos_dis   = (int*)carve(NDI);
  int* pos_drug  = (int*)carve(NDR);
  int* csr_d2di  = (int*)carve(NE);
  int* csr_di2dr = (int*)carve(NE);
  int* bsum_dis  = (int*)carve(256);
  int* bsum_drug = (int*)carve(256);
  int* bp_drug   = (int*)carve(NB);
  int* bp_dis    = (int*)carve(NB);

  // big split-bf16 buffers (compact, list-position indexed)
  unsigned short* aggh_dis  = carveU((size_t)NDI * HD);  // L0 agg -> overwritten in place by dis1_s0
  unsigned short* aggl_dis  = carveU((size_t)NDI * HD);
  unsigned short* aggh_drug = carveU((size_t)NDR * HD);  // L0 agg -> overwritten in place by drug1_s1
  unsigned short* aggl_drug = carveU((size_t)NDR * HD);
  // batch-sized split buffers
  unsigned short* d1bh = carveU((size_t)NB * HD);  // drug1 (stack0) at batch rows
  unsigned short* d1bl = carveU((size_t)NB * HD);
  unsigned short* s1bh = carveU((size_t)NB * HD);  // dis1 (stack1) at batch rows
  unsigned short* s1bl = carveU((size_t)NB * HD);
  unsigned short* aBdrh = carveU((size_t)NB * HD); // L1 agg at batch drug rows
  unsigned short* aBdrl = carveU((size_t)NB * HD);
  unsigned short* aBdih = carveU((size_t)NB * HD); // L1 agg at batch disease rows
  unsigned short* aBdil = carveU((size_t)NB * HD);
  unsigned short* deh = carveU((size_t)NB * HD);   // drug_emb split
  unsigned short* del = carveU((size_t)NB * HD);
  unsigned short* seh = carveU((size_t)NB * HD);   // dis_emb split
  unsigned short* sel = carveU((size_t)NB * HD);
  unsigned short* h1h = carveU((size_t)NB * 2 * HD);
  unsigned short* h1l = carveU((size_t)NB * 2 * HD);
  // weights (split)
  unsigned short* WLh = carveU(6 * 16384);
  unsigned short* WLl = carveU(6 * 16384);
  unsigned short* WRh = carveU(6 * 16384);
  unsigned short* WRl = carveU(6 * 16384);
  unsigned short* W2h = carveU(32768);
  unsigned short* W2l = carveU(32768);
  unsigned short* Amh = carveU(32768);
  unsigned short* Aml = carveU(32768);
  unsigned short* Bmh = carveU(32768);
  unsigned short* Bml = carveU(32768);
  // f32 small
  float* Wfold = carve(2 * HD * HD);
  float* bfold = carve(2 * HD);
  float* bc    = carve(2 * HD);
  float* h2    = carve((size_t)NB * HD);

  dim3 blk(256);
  const size_t WS = 16384;  // one 128x128 weight slot (elements)
  const int EB = (NE + 255) / 256;

  hipMemsetAsync(cnt_dis, 0, zero_bytes, stream);

  // weight prep (independent of graph work)
  fold_attn<<<256, 128, 0, stream>>>(attn_Win, attn_bin, attn_Wout, attn_bout, Wfold, bfold);
  fold_mlp<<<256, 128, 0, stream>>>(W1, b1, Wfold, bfold, Amh, Aml, Bmh, Bml, bc);
  split_weights<<<512, blk, 0, stream>>>(Wl, Wr, W2, WLh, WLl, WRh, WRl, W2h, W2l);

  // demand marking (edge-parallel, no CSR needed)
  batch_mark<<<(2 * NB + 255) / 256, blk, 0, stream>>>(drug_idx, dis_idx, fb_drug, fb_dis, fd_drug, fd_dis);
  edge_mark<<<dim3(EB, 2), blk, 0, stream>>>(src_d2di, dst_d2di, src_di2dr, dst_di2dr,
                                             fb_dis, fb_drug, fd_drug, fd_dis);

  // filtered degree counts, scans, filtered CSR
  count_f<<<dim3(EB, 2), blk, 0, stream>>>(dst_d2di, dst_di2dr, fd_dis, fd_drug, cnt_dis, cnt_drug);
  scan1y<<<dim3((NDR + 1023) / 1024, 2), blk, 0, stream>>>(cnt_dis, NDI, off_dis, bsum_dis,
                                                           cnt_drug, NDR, off_drug, bsum_drug);
  scan2<<<2, blk, 0, stream>>>(bsum_dis, (NDI + 1023) / 1024, bsum_drug, (NDR + 1023) / 1024);
  scan3y<<<dim3((NDR + 255) / 256, 2), blk, 0, stream>>>(off_dis, NDI, bsum_dis, off_drug, NDR, bsum_drug);
  csr_f<<<dim3(EB, 2), blk, 0, stream>>>(src_d2di, dst_d2di, src_di2dr, dst_di2dr, NE,
                                         fd_dis, fd_drug,
                                         off_dis, cursor_dis, csr_d2di,
                                         off_drug, cursor_drug, csr_di2dr);

  // compact demand flags -> lists + positions; batch positions
  compact2<<<dim3((NDR + 255) / 256, 2), blk, 0, stream>>>(fd_dis, NDI, list_dis, pos_dis, nctr + 0,
                                                           fd_drug, NDR, list_drug, pos_drug, nctr + 1);
  batchpos_k<<<(2 * NB + 255) / 256, blk, 0, stream>>>(drug_idx, dis_idx, pos_drug, pos_dis, bp_drug, bp_dis);

  // layer-0 mean aggregation at list positions (both directions, one dispatch)
  gather_f2s<<<dim3((NDR * 32 + 255) / 256, 2), blk, 0, stream>>>(
      emb_drug, csr_d2di, off_dis, cnt_dis, list_dis, nctr + 0, aggh_dis, aggl_dis,
      emb_dis, csr_di2dr, off_drug, cnt_drug, list_drug, nctr + 1, aggh_drug, aggl_drug);

  GemmArgs z{};  // zero template
  auto mk = [&](const unsigned short* X1h_, const unsigned short* X1l_,
                const unsigned short* X2h_, const unsigned short* X2l_, const float* x2f,
                const unsigned short* Wah_, const unsigned short* Wal_,
                const unsigned short* Wbh_, const unsigned short* Wbl_,
                const float* bias_, const int* map1_, const int* map2_, const int* nDev,
                unsigned short* Oh_, unsigned short* Ol_, float* Of_,
                int nMax, int K_, int J_, int relu_) {
    GemmArgs g = z;
    g.X1h = X1h_; g.X1l = X1l_; g.X2h = X2h_; g.X2l = X2l_; g.x2f32 = x2f;
    g.Wah = Wah_; g.Wal = Wal_; g.Wbh = Wbh_; g.Wbl = Wbl_;
    g.bias = bias_; g.map1 = map1_; g.map2 = map2_; g.nRowsDev = nDev;
    g.Oh = Oh_; g.Ol = Ol_; g.Of32 = Of_;
    g.nRowsMax = nMax; g.K = K_; g.Jtot = J_; g.relu = relu_;
    return g;
  };

  // L0 batch pair: dis1b (stack1, W idx4 -> slot3) + drug1b (stack0, W idx1 -> slot1)
  {
    GemmArgs a = mk(aggh_dis, aggl_dis, nullptr, nullptr, emb_dis,
                    WLh + 3 * WS, WLl + 3 * WS, WRh + 3 * WS, WRl + 3 * WS, bl + 4 * HD,
                    bp_dis, dis_idx, nullptr, s1bh, s1bl, nullptr, NB, 128, 128, 1);
    GemmArgs b = mk(aggh_drug, aggl_drug, nullptr, nullptr, emb_drug,
                    WLh + 1 * WS, WLl + 1 * WS, WRh + 1 * WS, WRl + 1 * WS, bl + 1 * HD,
                    bp_drug, drug_idx, nullptr, d1bh, d1bl, nullptr, NB, 128, 128, 1);
    mfma_pair<true><<<dim3(NB / 64 * 2, 1), blk, 0, stream>>>(a, b, NB / 64);
  }

  // L0 list pair (in-place over agg buffers): dis1_s0 (slot0) + drug1_s1 (slot4)
  {
    const int agx = (NDI + 63) / 64, bgx = (NDR + 63) / 64;
    GemmArgs a = mk(aggh_dis, aggl_dis, nullptr, nullptr, emb_dis,
                    WLh + 0 * WS, WLl + 0 * WS, WRh + 0 * WS, WRl + 0 * WS, bl + 0 * HD,
                    nullptr, list_dis, nctr + 0, aggh_dis, aggl_dis, nullptr, NDI, 128, 128, 1);
    GemmArgs b = mk(aggh_drug, aggl_drug, nullptr, nullptr, emb_drug,
                    WLh + 4 * WS, WLl + 4 * WS, WRh + 4 * WS, WRl + 4 * WS, bl + 5 * HD,
                    nullptr, list_drug, nctr + 1, aggh_drug, aggl_drug, nullptr, NDR, 128, 128, 1);
    mfma_pair<true><<<dim3(agx + bgx, 1), blk, 0, stream>>>(a, b, agx);
  }

  // layer-1 mean aggregation at batch rows (agg buffers now hold transformed L0 outputs)
  gather_s2s<<<dim3((NB * 32) / 256, 2), blk, 0, stream>>>(
      aggh_dis, aggl_dis, csr_di2dr, off_drug, cnt_drug, pos_dis, drug_idx, aBdrh, aBdrl,
      aggh_drug, aggl_drug, csr_d2di, off_dis, cnt_dis, pos_drug, dis_idx, aBdih, aBdil);

  // L1 pair: drug_emb (W idx3 -> slot2) + dis_emb (W idx6 -> slot5)
  {
    GemmArgs a = mk(aBdrh, aBdrl, d1bh, d1bl, nullptr,
                    WLh + 2 * WS, WLl + 2 * WS, WRh + 2 * WS, WRl + 2 * WS, bl + 3 * HD,
                    nullptr, nullptr, nullptr, deh, del, nullptr, NB, 128, 128, 1);
    GemmArgs b = mk(aBdih, aBdil, s1bh, s1bl, nullptr,
                    WLh + 5 * WS, WLl + 5 * WS, WRh + 5 * WS, WRl + 5 * WS, bl + 6 * HD,
                    nullptr, nullptr, nullptr, seh, sel, nullptr, NB, 128, 128, 1);
    mfma_pair<true><<<dim3(NB / 64 * 2, 1), blk, 0, stream>>>(a, b, NB / 64);
  }

  // link MLP (attention folded into Am/Bm/bc)
  {
    GemmArgs a = mk(deh, del, seh, sel, nullptr,
                    Amh, Aml, Bmh, Bml, bc,
                    nullptr, nullptr, nullptr, h1h, h1l, nullptr, NB, 128, 256, 1);
    mfma_pair<true><<<dim3(NB / 64, 2), blk, 0, stream>>>(a, a, NB / 64);
  }
  {
    GemmArgs a = mk(h1h, h1l, nullptr, nullptr, nullptr,
                    W2h, W2l, nullptr, nullptr, b2,
                    nullptr, nullptr, nullptr, nullptr, nullptr, h2, NB, 256, 128, 1);
    mfma_pair<false><<<dim3(NB / 64, 1), blk, 0, stream>>>(a, a, NB / 64);
  }
  final_dot<<<NB / 4, blk, 0, stream>>>(h2, W3, b3, out);

  (void)in_sizes; (void)n_in; (void)out_size; (void)ws_size;
}

// Round 6
// 493.532 us; speedup vs baseline: 9.5104x; 1.1563x over previous
//
#include <hip/hip_runtime.h>

namespace {

constexpr int HD  = 128;      // hidden dim
constexpr int NE  = 600000;   // edges per direction
constexpr int NDR = 200000;   // drugs
constexpr int NDI = 100000;   // diseases
constexpr int NB  = 8192;     // link batch

typedef __attribute__((ext_vector_type(8))) short short8;   // 8 bf16 in 4 VGPRs
typedef __attribute__((ext_vector_type(4))) float f32x4;

// ---- split-bf16 helpers: x = hi + lo (truncated), ~16 mantissa bits total ----
__device__ inline void splitf(float x, unsigned short& h, unsigned short& l) {
  unsigned u = __float_as_uint(x);
  h = (unsigned short)(u >> 16);
  float r = x - __uint_as_float(u & 0xffff0000u);   // exact residual
  l = (unsigned short)(__float_as_uint(r) >> 16);
}
__device__ inline void split4(const float4& v, uint2& ph, uint2& pl) {
  unsigned ux = __float_as_uint(v.x), uy = __float_as_uint(v.y);
  unsigned uz = __float_as_uint(v.z), uw = __float_as_uint(v.w);
  ph.x = (ux >> 16) | (uy & 0xffff0000u);
  ph.y = (uz >> 16) | (uw & 0xffff0000u);
  float rx = v.x - __uint_as_float(ux & 0xffff0000u);
  float ry = v.y - __uint_as_float(uy & 0xffff0000u);
  float rz = v.z - __uint_as_float(uz & 0xffff0000u);
  float rw = v.w - __uint_as_float(uw & 0xffff0000u);
  pl.x = (__float_as_uint(rx) >> 16) | (__float_as_uint(ry) & 0xffff0000u);
  pl.y = (__float_as_uint(rz) >> 16) | (__float_as_uint(rw) & 0xffff0000u);
}
// load 8 contiguous f32 and split into hi/lo bf16 fragments in-register
__device__ inline void split8(const float* p, short8& h8, short8& l8) {
  float4 v0 = *reinterpret_cast<const float4*>(p);
  float4 v1 = *reinterpret_cast<const float4*>(p + 4);
  uint2 h0, l0, h1, l1;
  split4(v0, h0, l0);
  split4(v1, h1, l1);
  union { unsigned u[4]; short8 s; } uh, ul;
  uh.u[0] = h0.x; uh.u[1] = h0.y; uh.u[2] = h1.x; uh.u[3] = h1.y;
  ul.u[0] = l0.x; ul.u[1] = l0.y; ul.u[2] = l1.x; ul.u[3] = l1.y;
  h8 = uh.s; l8 = ul.s;
}

// ---- MFMA B-fragment swizzled W layout ----
// Tile = 16 n-rows x 32 k. Within tile, element (n,k) lives at
// quad(k)*128 + (n&15)*8 + (k&7)  ==  lane*8 + j  for lane = (k>>3 & 3)*16 + (n&15).
// A wave's B-fragment load is then base + lane*8 (fully coalesced 1KB).
__device__ inline size_t swzW(int n, int k, int K) {
  return ((size_t)((n >> 4) * (K >> 5) + (k >> 5))) * 512 +
         (size_t)(((k >> 3) & 3) * 128 + (n & 15) * 8 + (k & 7));
}

// ---------------- batch flag + demand flag for batch nodes ----------------
__global__ void batch_mark(const int* __restrict__ drug_idx, const int* __restrict__ dis_idx,
                           int* __restrict__ fb_drug, int* __restrict__ fb_dis,
                           int* __restrict__ fd_drug, int* __restrict__ fd_dis) {
  int i = blockIdx.x * 256 + threadIdx.x;
  if (i < NB) { int g = drug_idx[i]; fb_drug[g] = 1; fd_drug[g] = 1; }
  else if (i < 2 * NB) { int g = dis_idx[i - NB]; fb_dis[g] = 1; fd_dis[g] = 1; }
}

// ---------------- edge-parallel demand mark: src of edges into batch dst ----------------
__global__ void edge_mark(const int* __restrict__ s0, const int* __restrict__ d0,   // d2di
                          const int* __restrict__ s1, const int* __restrict__ d1,   // di2dr
                          const int* __restrict__ fb_dis, const int* __restrict__ fb_drug,
                          int* __restrict__ fd_drug, int* __restrict__ fd_dis) {
  int e = blockIdx.x * 256 + threadIdx.x;
  if (e >= NE) return;
  if (blockIdx.y == 0) { if (fb_dis[d0[e]]) fd_drug[s0[e]] = 1; }
  else                 { if (fb_drug[d1[e]]) fd_dis[s1[e]] = 1; }
}

// ---------------- filtered degree counts (demanded dst only) ----------------
__global__ void count_f(const int* __restrict__ d0, const int* __restrict__ d1,
                        const int* __restrict__ fd_dis, const int* __restrict__ fd_drug,
                        int* __restrict__ c0, int* __restrict__ c1) {
  int e = blockIdx.x * 256 + threadIdx.x;
  if (e >= NE) return;
  if (blockIdx.y == 0) { int d = d0[e]; if (fd_dis[d]) atomicAdd(&c0[d], 1); }
  else                 { int d = d1[e]; if (fd_drug[d]) atomicAdd(&c1[d], 1); }
}

// ---------------- 3-phase exclusive scan, y selects dis/drug ----------------
__global__ void scan1y(const int* __restrict__ in0, int n0_, int* __restrict__ out0, int* __restrict__ bs0,
                       const int* __restrict__ in1, int n1_, int* __restrict__ out1, int* __restrict__ bs1) {
  const int* in; int n; int* outp; int* bs;
  if (blockIdx.y == 0) { in = in0; n = n0_; outp = out0; bs = bs0; }
  else                 { in = in1; n = n1_; outp = out1; bs = bs1; }
  if (blockIdx.x * 1024 >= n) return;
  __shared__ int s[256];
  int t = threadIdx.x;
  int idx = blockIdx.x * 1024 + t * 4;
  int4 v = make_int4(0, 0, 0, 0);
  if (idx + 3 < n) v = *reinterpret_cast<const int4*>(in + idx);
  else {
    if (idx     < n) v.x = in[idx];
    if (idx + 1 < n) v.y = in[idx + 1];
    if (idx + 2 < n) v.z = in[idx + 2];
    if (idx + 3 < n) v.w = in[idx + 3];
  }
  int tsum = v.x + v.y + v.z + v.w;
  s[t] = tsum;
  __syncthreads();
  for (int o = 1; o < 256; o <<= 1) {
    int x = (t >= o) ? s[t - o] : 0;
    __syncthreads();
    s[t] += x;
    __syncthreads();
  }
  int excl = s[t] - tsum;
  if (idx     < n) outp[idx]     = excl;
  if (idx + 1 < n) outp[idx + 1] = excl + v.x;
  if (idx + 2 < n) outp[idx + 2] = excl + v.x + v.y;
  if (idx + 3 < n) outp[idx + 3] = excl + v.x + v.y + v.z;
  if (t == 255) bs[blockIdx.x] = s[255];
}

__global__ void scan2(int* __restrict__ bs0, int nb0, int* __restrict__ bs1, int nb1) {
  int* bsum = (blockIdx.x == 0) ? bs0 : bs1;
  int nb = (blockIdx.x == 0) ? nb0 : nb1;
  __shared__ int s[256];
  int t = threadIdx.x;
  int v = (t < nb) ? bsum[t] : 0;
  s[t] = v;
  __syncthreads();
  for (int o = 1; o < 256; o <<= 1) {
    int x = (t >= o) ? s[t - o] : 0;
    __syncthreads();
    s[t] += x;
    __syncthreads();
  }
  if (t < nb) bsum[t] = s[t] - v;
}

__global__ void scan3y(int* __restrict__ out0, int n0_, const int* __restrict__ bs0,
                       int* __restrict__ out1, int n1_, const int* __restrict__ bs1) {
  int* outp; int n; const int* bs;
  if (blockIdx.y == 0) { outp = out0; n = n0_; bs = bs0; }
  else                 { outp = out1; n = n1_; bs = bs1; }
  int i = blockIdx.x * 256 + threadIdx.x;
  if (i < n) outp[i] += bs[i >> 10];
}

// ---------------- filtered CSR bucket scatter ----------------
__global__ void csr_f(const int* __restrict__ s0, const int* __restrict__ d0,
                      const int* __restrict__ s1, const int* __restrict__ d1, int nE,
                      const int* __restrict__ fd_dis, const int* __restrict__ fd_drug,
                      const int* __restrict__ off0, int* __restrict__ cur0, int* __restrict__ csr0,
                      const int* __restrict__ off1, int* __restrict__ cur1, int* __restrict__ csr1) {
  int e = blockIdx.x * 256 + threadIdx.x;
  if (e >= nE) return;
  if (blockIdx.y == 0) {
    int d = d0[e];
    if (fd_dis[d]) csr0[off0[d] + atomicAdd(&cur0[d], 1)] = s0[e];
  } else {
    int d = d1[e];
    if (fd_drug[d]) csr1[off1[d] + atomicAdd(&cur1[d], 1)] = s1[e];
  }
}

// ---------------- compact flags -> list + pos (both sides) ----------------
__global__ void compact2(const int* __restrict__ f0, int n0_, int* __restrict__ l0,
                         int* __restrict__ p0, int* __restrict__ c0,
                         const int* __restrict__ f1, int n1_, int* __restrict__ l1,
                         int* __restrict__ p1, int* __restrict__ c1) {
  int i = blockIdx.x * 256 + threadIdx.x;
  if (blockIdx.y == 0) {
    if (i < n0_ && f0[i]) { int p = atomicAdd(c0, 1); l0[p] = i; p0[i] = p; }
  } else {
    if (i < n1_ && f1[i]) { int p = atomicAdd(c1, 1); l1[p] = i; p1[i] = p; }
  }
}

// ---------------- batch node -> list position ----------------
__global__ void batchpos_k(const int* __restrict__ drug_idx, const int* __restrict__ dis_idx,
                           const int* __restrict__ pos_drug, const int* __restrict__ pos_dis,
                           int* __restrict__ bp_drug, int* __restrict__ bp_dis) {
  int i = blockIdx.x * 256 + threadIdx.x;
  if (i < NB) bp_drug[i] = pos_drug[drug_idx[i]];
  else if (i < 2 * NB) { int j = i - NB; bp_dis[j] = pos_dis[dis_idx[j]]; }
}

// ---------------- L0 gather (paired, y=direction): f32 in, split mean out at list pos ----------------
__global__ void gather_f2s(const float* __restrict__ x0, const int* __restrict__ csr0,
                           const int* __restrict__ off0, const int* __restrict__ cnt0,
                           const int* __restrict__ list0, const int* __restrict__ n0Dev,
                           unsigned short* __restrict__ oh0, unsigned short* __restrict__ ol0,
                           const float* __restrict__ x1, const int* __restrict__ csr1,
                           const int* __restrict__ off1, const int* __restrict__ cnt1,
                           const int* __restrict__ list1, const int* __restrict__ n1Dev,
                           unsigned short* __restrict__ oh1, unsigned short* __restrict__ ol1) {
  const float* x; const int *csr, *offp, *cnt, *list, *nDev;
  unsigned short *oh, *ol;
  if (blockIdx.y == 0) { x = x0; csr = csr0; offp = off0; cnt = cnt0; list = list0; nDev = n0Dev; oh = oh0; ol = ol0; }
  else                 { x = x1; csr = csr1; offp = off1; cnt = cnt1; list = list1; nDev = n1Dev; oh = oh1; ol = ol1; }
  int idx = blockIdx.x * 256 + threadIdx.x;
  int r = idx >> 5, c = idx & 31;
  if (r >= *nDev) return;
  int g = list[r];
  int o = offp[g], n = cnt[g];
  float4 acc = make_float4(0.f, 0.f, 0.f, 0.f);
  for (int j = 0; j < n; ++j) {
    int s = csr[o + j];
    float4 v = reinterpret_cast<const float4*>(x + (size_t)s * HD)[c];
    acc.x += v.x; acc.y += v.y; acc.z += v.z; acc.w += v.w;
  }
  float inv = 1.0f / (float)max(n, 1);
  float4 m = make_float4(acc.x * inv, acc.y * inv, acc.z * inv, acc.w * inv);
  uint2 ph, pl;
  split4(m, ph, pl);
  reinterpret_cast<uint2*>(oh + (size_t)r * HD)[c] = ph;
  reinterpret_cast<uint2*>(ol + (size_t)r * HD)[c] = pl;
}

// ---------------- L1 gather (paired): split rows (pos-indexed) in, split mean out at batch row ----
__global__ void gather_s2s(const unsigned short* __restrict__ xh0, const unsigned short* __restrict__ xl0,
                           const int* __restrict__ csr0, const int* __restrict__ off0,
                           const int* __restrict__ cnt0, const int* __restrict__ pos0,
                           const int* __restrict__ bidx0,
                           unsigned short* __restrict__ oh0, unsigned short* __restrict__ ol0,
                           const unsigned short* __restrict__ xh1, const unsigned short* __restrict__ xl1,
                           const int* __restrict__ csr1, const int* __restrict__ off1,
                           const int* __restrict__ cnt1, const int* __restrict__ pos1,
                           const int* __restrict__ bidx1,
                           unsigned short* __restrict__ oh1, unsigned short* __restrict__ ol1) {
  const unsigned short *xh, *xl; const int *csr, *offp, *cnt, *pos, *bidx;
  unsigned short *oh, *ol;
  if (blockIdx.y == 0) { xh = xh0; xl = xl0; csr = csr0; offp = off0; cnt = cnt0; pos = pos0; bidx = bidx0; oh = oh0; ol = ol0; }
  else                 { xh = xh1; xl = xl1; csr = csr1; offp = off1; cnt = cnt1; pos = pos1; bidx = bidx1; oh = oh1; ol = ol1; }
  int idx = blockIdx.x * 256 + threadIdx.x;
  int r = idx >> 5, c = idx & 31;
  if (r >= NB) return;
  int g = bidx[r];
  int o = offp[g], n = cnt[g];
  float4 acc = make_float4(0.f, 0.f, 0.f, 0.f);
  for (int j = 0; j < n; ++j) {
    int p = pos[csr[o + j]];
    uint2 hh = reinterpret_cast<const uint2*>(xh + (size_t)p * HD)[c];
    uint2 ll = reinterpret_cast<const uint2*>(xl + (size_t)p * HD)[c];
    acc.x += __uint_as_float(hh.x << 16) + __uint_as_float(ll.x << 16);
    acc.y += __uint_as_float(hh.x & 0xffff0000u) + __uint_as_float(ll.x & 0xffff0000u);
    acc.z += __uint_as_float(hh.y << 16) + __uint_as_float(ll.y << 16);
    acc.w += __uint_as_float(hh.y & 0xffff0000u) + __uint_as_float(ll.y & 0xffff0000u);
  }
  float inv = 1.0f / (float)max(n, 1);
  float4 m = make_float4(acc.x * inv, acc.y * inv, acc.z * inv, acc.w * inv);
  uint2 ph, pl;
  split4(m, ph, pl);
  reinterpret_cast<uint2*>(oh + (size_t)r * HD)[c] = ph;
  reinterpret_cast<uint2*>(ol + (size_t)r * HD)[c] = pl;
}

// ---------------- split static weights into B-fragment-swizzled layout ----------------
__global__ void split_weights(const float* __restrict__ Wl, const float* __restrict__ Wr,
                              const float* __restrict__ W2,
                              unsigned short* __restrict__ WLh, unsigned short* __restrict__ WLl,
                              unsigned short* __restrict__ WRh, unsigned short* __restrict__ WRl,
                              unsigned short* __restrict__ W2h, unsigned short* __restrict__ W2l) {
  const int widx[6] = {0, 1, 3, 4, 5, 6};
  int i = blockIdx.x * 256 + threadIdx.x;
  if (i < 98304) {
    int m = i >> 14, e = i & 16383;
    int n = e >> 7, k = e & 127;
    size_t o = (size_t)m * 16384 + swzW(n, k, 128);
    splitf(Wl[(size_t)widx[m] * 16384 + e], WLh[o], WLl[o]);
    splitf(Wr[(size_t)widx[m] * 16384 + e], WRh[o], WRl[o]);
  } else if (i < 131072) {
    int j = i - 98304;
    int n = j >> 8, k = j & 255;
    size_t o = swzW(n, k, 256);
    splitf(W2[j], W2h[o], W2l[o]);
  }
}

// ---------------- MFMA dual GEMM (pairable): LDS-staged X, swizzled W ----------------
struct GemmArgs {
  const unsigned short* X1h; const unsigned short* X1l;
  const unsigned short* X2h; const unsigned short* X2l;  // used when x2f32 == nullptr
  const float* x2f32;                                    // f32 X2 with in-register split
  const unsigned short* Wah; const unsigned short* Wal;  // swizzled (swzW)
  const unsigned short* Wbh; const unsigned short* Wbl;  // swizzled (swzW)
  const float* bias;
  const int* map1; const int* map2;
  const int* nRowsDev;
  unsigned short* Oh; unsigned short* Ol;
  float* Of32;
  int nRowsMax; int K; int Jtot; int relu;
};

template <bool DUAL>
__device__ inline void gemm_body(const GemmArgs& A, int bx, int by, int tid) {
  // LDS: 64 rows x 64-k chunk, +8 ushort pad -> row stride 144B (16B aligned, 2-way banks = free)
  __shared__ unsigned short sX1h[64][72];
  __shared__ unsigned short sX1l[64][72];
  __shared__ unsigned short sX2h[DUAL ? 64 : 1][72];
  __shared__ unsigned short sX2l[DUAL ? 64 : 1][72];

  const int nRows = A.nRowsDev ? *A.nRowsDev : A.nRowsMax;
  const int row0 = bx * 64;
  if (row0 >= nRows) return;
  const int colSlab = by * 128;
  if (colSlab >= A.Jtot) return;
  const int lane = tid & 63;
  const int wv = tid >> 6;
  const int quad = lane >> 4, m16 = lane & 15;
  const int n0 = colSlab + wv * 32;
  const int K = A.K;

  // staging role: 4 threads per row, 16 elements each
  const int sr = tid >> 2;
  const int sk = (tid & 3) * 16;
  int gsrc = row0 + sr;
  if (gsrc > nRows - 1) gsrc = nRows - 1;
  const int sg1 = A.map1 ? A.map1[gsrc] : gsrc;
  const int sg2 = DUAL ? (A.map2 ? A.map2[gsrc] : gsrc) : 0;

  f32x4 acc[4][2];
#pragma unroll
  for (int ct = 0; ct < 2; ++ct) {
    float b = A.bias[n0 + ct * 16 + m16];
    f32x4 bb = {b, b, b, b};
#pragma unroll
    for (int rt = 0; rt < 4; ++rt) acc[rt][ct] = bb;
  }

  for (int kc = 0; kc < K; kc += 64) {
    // ---- stage X chunk into LDS (coalesced) ----
    {
      const unsigned short* p = A.X1h + (size_t)sg1 * K + kc + sk;
      *reinterpret_cast<short8*>(&sX1h[sr][sk])     = *reinterpret_cast<const short8*>(p);
      *reinterpret_cast<short8*>(&sX1h[sr][sk + 8]) = *reinterpret_cast<const short8*>(p + 8);
      const unsigned short* q = A.X1l + (size_t)sg1 * K + kc + sk;
      *reinterpret_cast<short8*>(&sX1l[sr][sk])     = *reinterpret_cast<const short8*>(q);
      *reinterpret_cast<short8*>(&sX1l[sr][sk + 8]) = *reinterpret_cast<const short8*>(q + 8);
    }
    if (DUAL) {
      if (A.x2f32) {
        const float* p = A.x2f32 + (size_t)sg2 * K + kc + sk;
        short8 h0, l0, h1, l1;
        split8(p, h0, l0);
        split8(p + 8, h1, l1);
        *reinterpret_cast<short8*>(&sX2h[sr][sk])     = h0;
        *reinterpret_cast<short8*>(&sX2h[sr][sk + 8]) = h1;
        *reinterpret_cast<short8*>(&sX2l[sr][sk])     = l0;
        *reinterpret_cast<short8*>(&sX2l[sr][sk + 8]) = l1;
      } else {
        const unsigned short* p = A.X2h + (size_t)sg2 * K + kc + sk;
        *reinterpret_cast<short8*>(&sX2h[sr][sk])     = *reinterpret_cast<const short8*>(p);
        *reinterpret_cast<short8*>(&sX2h[sr][sk + 8]) = *reinterpret_cast<const short8*>(p + 8);
        const unsigned short* q = A.X2l + (size_t)sg2 * K + kc + sk;
        *reinterpret_cast<short8*>(&sX2l[sr][sk])     = *reinterpret_cast<const short8*>(q);
        *reinterpret_cast<short8*>(&sX2l[sr][sk + 8]) = *reinterpret_cast<const short8*>(q + 8);
      }
    }
    __syncthreads();

    // ---- compute: 2 MFMA k-steps per chunk ----
#pragma unroll
    for (int kk = 0; kk < 64; kk += 32) {
      const int ktile = (kc + kk) >> 5;
      short8 bah[2], bal[2], bbh[2], bbl[2];
#pragma unroll
      for (int ct = 0; ct < 2; ++ct) {
        size_t wo = ((size_t)(((n0 + ct * 16) >> 4) * (K >> 5) + ktile)) * 512 + (size_t)lane * 8;
        bah[ct] = *reinterpret_cast<const short8*>(A.Wah + wo);
        bal[ct] = *reinterpret_cast<const short8*>(A.Wal + wo);
        if (DUAL) {
          bbh[ct] = *reinterpret_cast<const short8*>(A.Wbh + wo);
          bbl[ct] = *reinterpret_cast<const short8*>(A.Wbl + wo);
        }
      }
#pragma unroll
      for (int rt = 0; rt < 4; ++rt) {
        const int xr = rt * 16 + m16;
        const int xo = kk + quad * 8;
        short8 a1h = *reinterpret_cast<const short8*>(&sX1h[xr][xo]);
        short8 a1l = *reinterpret_cast<const short8*>(&sX1l[xr][xo]);
#pragma unroll
        for (int ct = 0; ct < 2; ++ct) {
          acc[rt][ct] = __builtin_amdgcn_mfma_f32_16x16x32_bf16(a1h, bah[ct], acc[rt][ct], 0, 0, 0);
          acc[rt][ct] = __builtin_amdgcn_mfma_f32_16x16x32_bf16(a1h, bal[ct], acc[rt][ct], 0, 0, 0);
          acc[rt][ct] = __builtin_amdgcn_mfma_f32_16x16x32_bf16(a1l, bah[ct], acc[rt][ct], 0, 0, 0);
        }
        if (DUAL) {
          short8 a2h = *reinterpret_cast<const short8*>(&sX2h[xr][xo]);
          short8 a2l = *reinterpret_cast<const short8*>(&sX2l[xr][xo]);
#pragma unroll
          for (int ct = 0; ct < 2; ++ct) {
            acc[rt][ct] = __builtin_amdgcn_mfma_f32_16x16x32_bf16(a2h, bbh[ct], acc[rt][ct], 0, 0, 0);
            acc[rt][ct] = __builtin_amdgcn_mfma_f32_16x16x32_bf16(a2h, bbl[ct], acc[rt][ct], 0, 0, 0);
            acc[rt][ct] = __builtin_amdgcn_mfma_f32_16x16x32_bf16(a2l, bbh[ct], acc[rt][ct], 0, 0, 0);
          }
        }
      }
    }
    __syncthreads();
  }

  // epilogue: D[m = quad*4+i][n = m16] per 16x16 tile
#pragma unroll
  for (int rt = 0; rt < 4; ++rt) {
#pragma unroll
    for (int i = 0; i < 4; ++i) {
      int m = row0 + rt * 16 + quad * 4 + i;
      if (m < nRows) {
#pragma unroll
        for (int ct = 0; ct < 2; ++ct) {
          float v = acc[rt][ct][i];
          if (A.relu) v = fmaxf(v, 0.0f);
          size_t o = (size_t)m * A.Jtot + n0 + ct * 16 + m16;
          if (A.Of32) A.Of32[o] = v;
          if (A.Oh) {
            unsigned short h, l;
            splitf(v, h, l);
            A.Oh[o] = h; A.Ol[o] = l;
          }
        }
      }
    }
  }
}

template <bool DUAL>
__global__ __launch_bounds__(256) void mfma_pair(GemmArgs a, GemmArgs b, int agx) {
  int bx = blockIdx.x;
  if (bx < agx) gemm_body<DUAL>(a, bx, blockIdx.y, threadIdx.x);
  else          gemm_body<DUAL>(b, bx - agx, blockIdx.y, threadIdx.x);
}

// ---------------- fold attention (len-1 softmax == identity): Wfold = Wout @ Wv ------
__global__ void fold_attn(const float* __restrict__ Win, const float* __restrict__ bin,
                          const float* __restrict__ Wout, const float* __restrict__ bout,
                          float* __restrict__ Wfold, float* __restrict__ bfold) {
  int s = blockIdx.x >> 7, m = blockIdx.x & 127, k = threadIdx.x;
  const float* wout_row = Wout + ((size_t)s * HD + m) * HD;
  const float* wv = Win + (size_t)s * 3 * HD * HD + 2 * HD * HD;
  float acc = 0.0f;
  for (int u = 0; u < HD; ++u) acc += wout_row[u] * wv[u * HD + k];
  Wfold[((size_t)s * HD + m) * HD + k] = acc;
  if (k == 0) {
    const float* bv = bin + (size_t)s * 3 * HD + 2 * HD;
    float b = bout[s * HD + m];
    for (int u = 0; u < HD; ++u) b += wout_row[u] * bv[u];
    bfold[s * HD + m] = b;
  }
}

// ---------------- fold attn into MLP layer 1, emit swizzled split-bf16 A/B ----------------
__global__ void fold_mlp(const float* __restrict__ W1, const float* __restrict__ b1,
                         const float* __restrict__ Wfold, const float* __restrict__ bfold,
                         unsigned short* __restrict__ Ah, unsigned short* __restrict__ Al,
                         unsigned short* __restrict__ Bh, unsigned short* __restrict__ Bl,
                         float* __restrict__ bc) {
  int r = blockIdx.x, k = threadIdx.x;
  const float* w1r = W1 + (size_t)r * 512;
  const float* Wf0 = Wfold;            // module 0: drug_att <- dis_emb
  const float* Wf1 = Wfold + HD * HD;  // module 1: dis_att  <- drug_emb
  float accA = 0.0f, accB = 0.0f;
  for (int m = 0; m < HD; ++m) {
    accA += w1r[384 + m] * Wf1[m * HD + k];
    accB += w1r[256 + m] * Wf0[m * HD + k];
  }
  size_t o = swzW(r, k, 128);
  splitf(w1r[k] + accA, Ah[o], Al[o]);
  splitf(w1r[128 + k] + accB, Bh[o], Bl[o]);
  if (k == 0) {
    float b = b1[r];
    for (int m = 0; m < HD; ++m) b += w1r[256 + m] * bfold[m] + w1r[384 + m] * bfold[HD + m];
    bc[r] = b;
  }
}

// ---------------- final dot: out[b] = h2[b] . W3 + b3 ----------------
__global__ void final_dot(const float* __restrict__ h2, const float* __restrict__ W3,
                          const float* __restrict__ b3, float* __restrict__ out) {
  int b = blockIdx.x * 4 + (threadIdx.x >> 6);
  int lane = threadIdx.x & 63;
  float2 hv = reinterpret_cast<const float2*>(h2 + (size_t)b * HD)[lane];
  float2 wv = reinterpret_cast<const float2*>(W3)[lane];
  float v = hv.x * wv.x + hv.y * wv.y;
  for (int off = 32; off; off >>= 1) v += __shfl_down(v, off);
  if (lane == 0) out[b] = v + b3[0];
}

}  // namespace

extern "C" void kernel_launch(void* const* d_in, const int* in_sizes, int n_in,
                              void* d_out, int out_size, void* d_ws, size_t ws_size,
                              hipStream_t stream) {
  const int* src_d2di  = (const int*)d_in[0];
  const int* dst_d2di  = (const int*)d_in[1];
  const int* src_di2dr = (const int*)d_in[2];
  const int* dst_di2dr = (const int*)d_in[3];
  const int* drug_idx  = (const int*)d_in[4];
  const int* dis_idx   = (const int*)d_in[5];
  const float* emb_drug = (const float*)d_in[6];
  const float* emb_dis  = (const float*)d_in[7];
  const float* Wl = (const float*)d_in[8];
  const float* bl = (const float*)d_in[9];
  const float* Wr = (const float*)d_in[10];
  const float* attn_Win  = (const float*)d_in[11];
  const float* attn_bin  = (const float*)d_in[12];
  const float* attn_Wout = (const float*)d_in[13];
  const float* attn_bout = (const float*)d_in[14];
  const float* W1 = (const float*)d_in[15];
  const float* b1 = (const float*)d_in[16];
  const float* W2 = (const float*)d_in[17];
  const float* b2 = (const float*)d_in[18];
  const float* W3 = (const float*)d_in[19];
  const float* b3 = (const float*)d_in[20];
  float* out = (float*)d_out;

  // ---- workspace carve (16B-aligned float units) ----
  float* ws = (float*)d_ws;
  size_t off = 0;
  auto carve = [&](size_t nfloats) {
    float* p = ws + off;
    off += (nfloats + 3) & ~(size_t)3;
    return p;
  };
  auto carveU = [&](size_t nush) { return (unsigned short*)carve((nush + 1) / 2); };

  // zeroed int region (one memset)
  int* cnt_dis     = (int*)carve(NDI);
  int* cnt_drug    = (int*)carve(NDR);
  int* cursor_dis  = (int*)carve(NDI);
  int* cursor_drug = (int*)carve(NDR);
  int* fb_dis      = (int*)carve(NDI);
  int* fb_drug     = (int*)carve(NDR);
  int* fd_dis      = (int*)carve(NDI);
  int* fd_drug     = (int*)carve(NDR);
  int* nctr        = (int*)carve(8);       // [0]=n_list_dis, [1]=n_list_drug
  const size_t zero_bytes = (4 * ((size_t)NDI + NDR) + 8) * 4;
  // not zeroed
  int* off_dis   = (int*)carve(NDI);
  int* off_drug  = (int*)carve(NDR);
  int* list_dis  = (int*)carve(NDI);
  int* list_drug = (int*)carve(NDR);
  int* pos_dis   = (int*)carve(NDI);
  int* pos_drug  = (int*)carve(NDR);
  int* csr_d2di  = (int*)carve(NE);
  int* csr_di2dr = (int*)carve(NE);
  int* bsum_dis  = (int*)carve(256);
  int* bsum_drug = (int*)carve(256);
  int* bp_drug   = (int*)carve(NB);
  int* bp_dis    = (int*)carve(NB);

  // big split-bf16 buffers (compact, list-position indexed)
  unsigned short* aggh_dis  = carveU((size_t)NDI * HD);  // L0 agg -> overwritten in place by dis1_s0
  unsigned short* aggl_dis  = carveU((size_t)NDI * HD);
  unsigned short* aggh_drug = carveU((size_t)NDR * HD);  // L0 agg -> overwritten in place by drug1_s1
  unsigned short* aggl_drug = carveU((size_t)NDR * HD);
  // batch-sized split buffers
  unsigned short* d1bh = carveU((size_t)NB * HD);  // drug1 (stack0) at batch rows
  unsigned short* d1bl = carveU((size_t)NB * HD);
  unsigned short* s1bh = carveU((size_t)NB * HD);  // dis1 (stack1) at batch rows
  unsigned short* s1bl = carveU((size_t)NB * HD);
  unsigned short* aBdrh = carveU((size_t)NB * HD); // L1 agg at batch drug rows
  unsigned short* aBdrl = carveU((size_t)NB * HD);
  unsigned short* aBdih = carveU((size_t)NB * HD); // L1 agg at batch disease rows
  unsigned short* aBdil = carveU((size_t)NB * HD);
  unsigned short* deh = carveU((size_t)NB * HD);   // drug_emb split
  unsigned short* del = carveU((size_t)NB * HD);
  unsigned short* seh = carveU((size_t)NB * HD);   // dis_emb split
  unsigned short* sel = carveU((size_t)NB * HD);
  unsigned short* h1h = carveU((size_t)NB * 2 * HD);
  unsigned short* h1l = carveU((size_t)NB * 2 * HD);
  // weights (split, B-fragment swizzled)
  unsigned short* WLh = carveU(6 * 16384);
  unsigned short* WLl = carveU(6 * 16384);
  unsigned short* WRh = carveU(6 * 16384);
  unsigned short* WRl = carveU(6 * 16384);
  unsigned short* W2h = carveU(32768);
  unsigned short* W2l = carveU(32768);
  unsigned short* Amh = carveU(32768);
  unsigned short* Aml = carveU(32768);
  unsigned short* Bmh = carveU(32768);
  unsigned short* Bml = carveU(32768);
  // f32 small
  float* Wfold = carve(2 * HD * HD);
  float* bfold = carve(2 * HD);
  float* bc    = carve(2 * HD);
  float* h2    = carve((size_t)NB * HD);

  dim3 blk(256);
  const size_t WS = 16384;  // one 128x128 weight slot (elements)
  const int EB = (NE + 255) / 256;

  hipMemsetAsync(cnt_dis, 0, zero_bytes, stream);

  // weight prep (independent of graph work)
  fold_attn<<<256, 128, 0, stream>>>(attn_Win, attn_bin, attn_Wout, attn_bout, Wfold, bfold);
  fold_mlp<<<256, 128, 0, stream>>>(W1, b1, Wfold, bfold, Amh, Aml, Bmh, Bml, bc);
  split_weights<<<512, blk, 0, stream>>>(Wl, Wr, W2, WLh, WLl, WRh, WRl, W2h, W2l);

  // demand marking (edge-parallel, no CSR needed)
  batch_mark<<<(2 * NB + 255) / 256, blk, 0, stream>>>(drug_idx, dis_idx, fb_drug, fb_dis, fd_drug, fd_dis);
  edge_mark<<<dim3(EB, 2), blk, 0, stream>>>(src_d2di, dst_d2di, src_di2dr, dst_di2dr,
                                             fb_dis, fb_drug, fd_drug, fd_dis);

  // filtered degree counts, scans, filtered CSR
  count_f<<<dim3(EB, 2), blk, 0, stream>>>(dst_d2di, dst_di2dr, fd_dis, fd_drug, cnt_dis, cnt_drug);
  scan1y<<<dim3((NDR + 1023) / 1024, 2), blk, 0, stream>>>(cnt_dis, NDI, off_dis, bsum_dis,
                                                           cnt_drug, NDR, off_drug, bsum_drug);
  scan2<<<2, blk, 0, stream>>>(bsum_dis, (NDI + 1023) / 1024, bsum_drug, (NDR + 1023) / 1024);
  scan3y<<<dim3((NDR + 255) / 256, 2), blk, 0, stream>>>(off_dis, NDI, bsum_dis, off_drug, NDR, bsum_drug);
  csr_f<<<dim3(EB, 2), blk, 0, stream>>>(src_d2di, dst_d2di, src_di2dr, dst_di2dr, NE,
                                         fd_dis, fd_drug,
                                         off_dis, cursor_dis, csr_d2di,
                                         off_drug, cursor_drug, csr_di2dr);

  // compact demand flags -> lists + positions; batch positions
  compact2<<<dim3((NDR + 255) / 256, 2), blk, 0, stream>>>(fd_dis, NDI, list_dis, pos_dis, nctr + 0,
                                                           fd_drug, NDR, list_drug, pos_drug, nctr + 1);
  batchpos_k<<<(2 * NB + 255) / 256, blk, 0, stream>>>(drug_idx, dis_idx, pos_drug, pos_dis, bp_drug, bp_dis);

  // layer-0 mean aggregation at list positions (both directions, one dispatch)
  gather_f2s<<<dim3((NDR * 32 + 255) / 256, 2), blk, 0, stream>>>(
      emb_drug, csr_d2di, off_dis, cnt_dis, list_dis, nctr + 0, aggh_dis, aggl_dis,
      emb_dis, csr_di2dr, off_drug, cnt_drug, list_drug, nctr + 1, aggh_drug, aggl_drug);

  GemmArgs z{};  // zero template
  auto mk = [&](const unsigned short* X1h_, const unsigned short* X1l_,
                const unsigned short* X2h_, const unsigned short* X2l_, const float* x2f,
                const unsigned short* Wah_, const unsigned short* Wal_,
                const unsigned short* Wbh_, const unsigned short* Wbl_,
                const float* bias_, const int* map1_, const int* map2_, const int* nDev,
                unsigned short* Oh_, unsigned short* Ol_, float* Of_,
                int nMax, int K_, int J_, int relu_) {
    GemmArgs g = z;
    g.X1h = X1h_; g.X1l = X1l_; g.X2h = X2h_; g.X2l = X2l_; g.x2f32 = x2f;
    g.Wah = Wah_; g.Wal = Wal_; g.Wbh = Wbh_; g.Wbl = Wbl_;
    g.bias = bias_; g.map1 = map1_; g.map2 = map2_; g.nRowsDev = nDev;
    g.Oh = Oh_; g.Ol = Ol_; g.Of32 = Of_;
    g.nRowsMax = nMax; g.K = K_; g.Jtot = J_; g.relu = relu_;
    return g;
  };

  // L0 batch pair: dis1b (stack1, W idx4 -> slot3) + drug1b (stack0, W idx1 -> slot1)
  {
    GemmArgs a = mk(aggh_dis, aggl_dis, nullptr, nullptr, emb_dis,
                    WLh + 3 * WS, WLl + 3 * WS, WRh + 3 * WS, WRl + 3 * WS, bl + 4 * HD,
                    bp_dis, dis_idx, nullptr, s1bh, s1bl, nullptr, NB, 128, 128, 1);
    GemmArgs b = mk(aggh_drug, aggl_drug, nullptr, nullptr, emb_drug,
                    WLh + 1 * WS, WLl + 1 * WS, WRh + 1 * WS, WRl + 1 * WS, bl + 1 * HD,
                    bp_drug, drug_idx, nullptr, d1bh, d1bl, nullptr, NB, 128, 128, 1);
    mfma_pair<true><<<dim3(NB / 64 * 2, 1), blk, 0, stream>>>(a, b, NB / 64);
  }

  // L0 list pair (in-place over agg buffers): dis1_s0 (slot0) + drug1_s1 (slot4)
  {
    const int agx = (NDI + 63) / 64, bgx = (NDR + 63) / 64;
    GemmArgs a = mk(aggh_dis, aggl_dis, nullptr, nullptr, emb_dis,
                    WLh + 0 * WS, WLl + 0 * WS, WRh + 0 * WS, WRl + 0 * WS, bl + 0 * HD,
                    nullptr, list_dis, nctr + 0, aggh_dis, aggl_dis, nullptr, NDI, 128, 128, 1);
    GemmArgs b = mk(aggh_drug, aggl_drug, nullptr, nullptr, emb_drug,
                    WLh + 4 * WS, WLl + 4 * WS, WRh + 4 * WS, WRl + 4 * WS, bl + 5 * HD,
                    nullptr, list_drug, nctr + 1, aggh_drug, aggl_drug, nullptr, NDR, 128, 128, 1);
    mfma_pair<true><<<dim3(agx + bgx, 1), blk, 0, stream>>>(a, b, agx);
  }

  // layer-1 mean aggregation at batch rows (agg buffers now hold transformed L0 outputs)
  gather_s2s<<<dim3((NB * 32) / 256, 2), blk, 0, stream>>>(
      aggh_dis, aggl_dis, csr_di2dr, off_drug, cnt_drug, pos_dis, drug_idx, aBdrh, aBdrl,
      aggh_drug, aggl_drug, csr_d2di, off_dis, cnt_dis, pos_drug, dis_idx, aBdih, aBdil);

  // L1 pair: drug_emb (W idx3 -> slot2) + dis_emb (W idx6 -> slot5)
  {
    GemmArgs a = mk(aBdrh, aBdrl, d1bh, d1bl, nullptr,
                    WLh + 2 * WS, WLl + 2 * WS, WRh + 2 * WS, WRl + 2 * WS, bl + 3 * HD,
                    nullptr, nullptr, nullptr, deh, del, nullptr, NB, 128, 128, 1);
    GemmArgs b = mk(aBdih, aBdil, s1bh, s1bl, nullptr,
                    WLh + 5 * WS, WLl + 5 * WS, WRh + 5 * WS, WRl + 5 * WS, bl + 6 * HD,
                    nullptr, nullptr, nullptr, seh, sel, nullptr, NB, 128, 128, 1);
    mfma_pair<true><<<dim3(NB / 64 * 2, 1), blk, 0, stream>>>(a, b, NB / 64);
  }

  // link MLP (attention folded into Am/Bm/bc)
  {
    GemmArgs a = mk(deh, del, seh, sel, nullptr,
                    Amh, Aml, Bmh, Bml, bc,
                    nullptr, nullptr, nullptr, h1h, h1l, nullptr, NB, 128, 256, 1);
    mfma_pair<true><<<dim3(NB / 64, 2), blk, 0, stream>>>(a, a, NB / 64);
  }
  {
    GemmArgs a = mk(h1h, h1l, nullptr, nullptr, nullptr,
                    W2h, W2l, nullptr, nullptr, b2,
                    nullptr, nullptr, nullptr, nullptr, nullptr, h2, NB, 256, 128, 1);
    mfma_pair<false><<<dim3(NB / 64, 1), blk, 0, stream>>>(a, a, NB / 64);
  }
  final_dot<<<NB / 4, blk, 0, stream>>>(h2, W3, b3, out);

  (void)in_sizes; (void)n_in; (void)out_size; (void)ws_size;
}

// Round 7
// 475.439 us; speedup vs baseline: 9.8723x; 1.0381x over previous
//
#include <hip/hip_runtime.h>

namespace {

constexpr int HD  = 128;      // hidden dim
constexpr int NE  = 600000;   // edges per direction
constexpr int NDR = 200000;   // drugs
constexpr int NDI = 100000;   // diseases
constexpr int NB  = 8192;     // link batch

typedef __attribute__((ext_vector_type(8))) short short8;   // 8 bf16 in 4 VGPRs
typedef __attribute__((ext_vector_type(4))) float f32x4;

// ---- split-bf16 helpers: x = hi + lo (truncated), ~16 mantissa bits total ----
__device__ inline void splitf(float x, unsigned short& h, unsigned short& l) {
  unsigned u = __float_as_uint(x);
  h = (unsigned short)(u >> 16);
  float r = x - __uint_as_float(u & 0xffff0000u);   // exact residual
  l = (unsigned short)(__float_as_uint(r) >> 16);
}
__device__ inline void split4(const float4& v, uint2& ph, uint2& pl) {
  unsigned ux = __float_as_uint(v.x), uy = __float_as_uint(v.y);
  unsigned uz = __float_as_uint(v.z), uw = __float_as_uint(v.w);
  ph.x = (ux >> 16) | (uy & 0xffff0000u);
  ph.y = (uz >> 16) | (uw & 0xffff0000u);
  float rx = v.x - __uint_as_float(ux & 0xffff0000u);
  float ry = v.y - __uint_as_float(uy & 0xffff0000u);
  float rz = v.z - __uint_as_float(uz & 0xffff0000u);
  float rw = v.w - __uint_as_float(uw & 0xffff0000u);
  pl.x = (__float_as_uint(rx) >> 16) | (__float_as_uint(ry) & 0xffff0000u);
  pl.y = (__float_as_uint(rz) >> 16) | (__float_as_uint(rw) & 0xffff0000u);
}
// load 8 contiguous f32 and split into hi/lo bf16 fragments in-register
__device__ inline void split8(const float* p, short8& h8, short8& l8) {
  float4 v0 = *reinterpret_cast<const float4*>(p);
  float4 v1 = *reinterpret_cast<const float4*>(p + 4);
  uint2 h0, l0, h1, l1;
  split4(v0, h0, l0);
  split4(v1, h1, l1);
  union { unsigned u[4]; short8 s; } uh, ul;
  uh.u[0] = h0.x; uh.u[1] = h0.y; uh.u[2] = h1.x; uh.u[3] = h1.y;
  ul.u[0] = l0.x; ul.u[1] = l0.y; ul.u[2] = l1.x; ul.u[3] = l1.y;
  h8 = uh.s; l8 = ul.s;
}

// ---- MFMA B-fragment swizzled W layout ----
// Tile = 16 n-rows x 32 k. Element (n,k) -> tile*512 + quad(k)*128 + (n&15)*8 + (k&7),
// so a wave's B-fragment load is base + lane*8 (fully coalesced 1KB).
__device__ inline size_t swzW(int n, int k, int K) {
  return ((size_t)((n >> 4) * (K >> 5) + (k >> 5))) * 512 +
         (size_t)(((k >> 3) & 3) * 128 + (n & 15) * 8 + (k & 7));
}

// ---------------- batch flag + demand flag for batch nodes ----------------
__global__ void batch_mark(const int* __restrict__ drug_idx, const int* __restrict__ dis_idx,
                           unsigned char* __restrict__ fb_drug, unsigned char* __restrict__ fb_dis,
                           unsigned char* __restrict__ fd_drug, unsigned char* __restrict__ fd_dis) {
  int i = blockIdx.x * 256 + threadIdx.x;
  if (i < NB) { int g = drug_idx[i]; fb_drug[g] = 1; fd_drug[g] = 1; }
  else if (i < 2 * NB) { int g = dis_idx[i - NB]; fb_dis[g] = 1; fd_dis[g] = 1; }
}

// ---------------- edge-parallel demand mark: src of edges into batch dst ----------------
__global__ void edge_mark(const int* __restrict__ s0, const int* __restrict__ d0,   // d2di
                          const int* __restrict__ s1, const int* __restrict__ d1,   // di2dr
                          const unsigned char* __restrict__ fb_dis,
                          const unsigned char* __restrict__ fb_drug,
                          unsigned char* __restrict__ fd_drug, unsigned char* __restrict__ fd_dis) {
  int e = blockIdx.x * 256 + threadIdx.x;
  if (e >= NE) return;
  if (blockIdx.y == 0) { if (fb_dis[d0[e]]) fd_drug[s0[e]] = 1; }
  else                 { if (fb_drug[d1[e]]) fd_dis[s1[e]] = 1; }
}

// ---------------- filtered degree counts (demanded dst only) ----------------
__global__ void count_f(const int* __restrict__ d0, const int* __restrict__ d1,
                        const unsigned char* __restrict__ fd_dis,
                        const unsigned char* __restrict__ fd_drug,
                        int* __restrict__ c0, int* __restrict__ c1) {
  int e = blockIdx.x * 256 + threadIdx.x;
  if (e >= NE) return;
  if (blockIdx.y == 0) { int d = d0[e]; if (fd_dis[d]) atomicAdd(&c0[d], 1); }
  else                 { int d = d1[e]; if (fd_drug[d]) atomicAdd(&c1[d], 1); }
}

// ---------------- 3-phase exclusive scan, y selects dis/drug ----------------
__global__ void scan1y(const int* __restrict__ in0, int n0_, int* __restrict__ out0, int* __restrict__ bs0,
                       const int* __restrict__ in1, int n1_, int* __restrict__ out1, int* __restrict__ bs1) {
  const int* in; int n; int* outp; int* bs;
  if (blockIdx.y == 0) { in = in0; n = n0_; outp = out0; bs = bs0; }
  else                 { in = in1; n = n1_; outp = out1; bs = bs1; }
  if (blockIdx.x * 1024 >= n) return;
  __shared__ int s[256];
  int t = threadIdx.x;
  int idx = blockIdx.x * 1024 + t * 4;
  int4 v = make_int4(0, 0, 0, 0);
  if (idx + 3 < n) v = *reinterpret_cast<const int4*>(in + idx);
  else {
    if (idx     < n) v.x = in[idx];
    if (idx + 1 < n) v.y = in[idx + 1];
    if (idx + 2 < n) v.z = in[idx + 2];
    if (idx + 3 < n) v.w = in[idx + 3];
  }
  int tsum = v.x + v.y + v.z + v.w;
  s[t] = tsum;
  __syncthreads();
  for (int o = 1; o < 256; o <<= 1) {
    int x = (t >= o) ? s[t - o] : 0;
    __syncthreads();
    s[t] += x;
    __syncthreads();
  }
  int excl = s[t] - tsum;
  if (idx     < n) outp[idx]     = excl;
  if (idx + 1 < n) outp[idx + 1] = excl + v.x;
  if (idx + 2 < n) outp[idx + 2] = excl + v.x + v.y;
  if (idx + 3 < n) outp[idx + 3] = excl + v.x + v.y + v.z;
  if (t == 255) bs[blockIdx.x] = s[255];
}

__global__ void scan2(int* __restrict__ bs0, int nb0, int* __restrict__ bs1, int nb1) {
  int* bsum = (blockIdx.x == 0) ? bs0 : bs1;
  int nb = (blockIdx.x == 0) ? nb0 : nb1;
  __shared__ int s[256];
  int t = threadIdx.x;
  int v = (t < nb) ? bsum[t] : 0;
  s[t] = v;
  __syncthreads();
  for (int o = 1; o < 256; o <<= 1) {
    int x = (t >= o) ? s[t - o] : 0;
    __syncthreads();
    s[t] += x;
    __syncthreads();
  }
  if (t < nb) bsum[t] = s[t] - v;
}

__global__ void scan3y(int* __restrict__ out0, int n0_, const int* __restrict__ bs0,
                       int* __restrict__ out1, int n1_, const int* __restrict__ bs1) {
  int* outp; int n; const int* bs;
  if (blockIdx.y == 0) { outp = out0; n = n0_; bs = bs0; }
  else                 { outp = out1; n = n1_; bs = bs1; }
  int i = blockIdx.x * 256 + threadIdx.x;
  if (i < n) outp[i] += bs[i >> 10];
}

// ---------------- filtered CSR bucket scatter ----------------
__global__ void csr_f(const int* __restrict__ s0, const int* __restrict__ d0,
                      const int* __restrict__ s1, const int* __restrict__ d1, int nE,
                      const unsigned char* __restrict__ fd_dis,
                      const unsigned char* __restrict__ fd_drug,
                      const int* __restrict__ off0, int* __restrict__ cur0, int* __restrict__ csr0,
                      const int* __restrict__ off1, int* __restrict__ cur1, int* __restrict__ csr1) {
  int e = blockIdx.x * 256 + threadIdx.x;
  if (e >= nE) return;
  if (blockIdx.y == 0) {
    int d = d0[e];
    if (fd_dis[d]) csr0[off0[d] + atomicAdd(&cur0[d], 1)] = s0[e];
  } else {
    int d = d1[e];
    if (fd_drug[d]) csr1[off1[d] + atomicAdd(&cur1[d], 1)] = s1[e];
  }
}

// ---------------- compact flags -> list + pos (both sides) ----------------
__global__ void compact2(const unsigned char* __restrict__ f0, int n0_, int* __restrict__ l0,
                         int* __restrict__ p0, int* __restrict__ c0,
                         const unsigned char* __restrict__ f1, int n1_, int* __restrict__ l1,
                         int* __restrict__ p1, int* __restrict__ c1) {
  int i = blockIdx.x * 256 + threadIdx.x;
  if (blockIdx.y == 0) {
    if (i < n0_ && f0[i]) { int p = atomicAdd(c0, 1); l0[p] = i; p0[i] = p; }
  } else {
    if (i < n1_ && f1[i]) { int p = atomicAdd(c1, 1); l1[p] = i; p1[i] = p; }
  }
}

// ---------------- batch node -> list position ----------------
__global__ void batchpos_k(const int* __restrict__ drug_idx, const int* __restrict__ dis_idx,
                           const int* __restrict__ pos_drug, const int* __restrict__ pos_dis,
                           int* __restrict__ bp_drug, int* __restrict__ bp_dis) {
  int i = blockIdx.x * 256 + threadIdx.x;
  if (i < NB) bp_drug[i] = pos_drug[drug_idx[i]];
  else if (i < 2 * NB) { int j = i - NB; bp_dis[j] = pos_dis[dis_idx[j]]; }
}

// ---------------- L0 gather (paired, y=direction): f32 in, split mean out at list pos ----------------
// 4-wide unrolled neighbor loop: batch index loads, then batch row loads (MLP),
// adds remain strictly sequential (numerics identical to serial loop).
__global__ void gather_f2s(const float* __restrict__ x0, const int* __restrict__ csr0,
                           const int* __restrict__ off0, const int* __restrict__ cnt0,
                           const int* __restrict__ list0, const int* __restrict__ n0Dev,
                           unsigned short* __restrict__ oh0, unsigned short* __restrict__ ol0,
                           const float* __restrict__ x1, const int* __restrict__ csr1,
                           const int* __restrict__ off1, const int* __restrict__ cnt1,
                           const int* __restrict__ list1, const int* __restrict__ n1Dev,
                           unsigned short* __restrict__ oh1, unsigned short* __restrict__ ol1) {
  const float* x; const int *csr, *offp, *cnt, *list, *nDev;
  unsigned short *oh, *ol;
  if (blockIdx.y == 0) { x = x0; csr = csr0; offp = off0; cnt = cnt0; list = list0; nDev = n0Dev; oh = oh0; ol = ol0; }
  else                 { x = x1; csr = csr1; offp = off1; cnt = cnt1; list = list1; nDev = n1Dev; oh = oh1; ol = ol1; }
  int idx = blockIdx.x * 256 + threadIdx.x;
  int r = idx >> 5, c = idx & 31;
  if (r >= *nDev) return;
  int g = list[r];
  int o = offp[g], n = cnt[g];
  float4 acc = make_float4(0.f, 0.f, 0.f, 0.f);
  int j = 0;
  for (; j + 4 <= n; j += 4) {
    int s0 = csr[o + j], s1 = csr[o + j + 1], s2 = csr[o + j + 2], s3 = csr[o + j + 3];
    float4 v0 = reinterpret_cast<const float4*>(x + (size_t)s0 * HD)[c];
    float4 v1 = reinterpret_cast<const float4*>(x + (size_t)s1 * HD)[c];
    float4 v2 = reinterpret_cast<const float4*>(x + (size_t)s2 * HD)[c];
    float4 v3 = reinterpret_cast<const float4*>(x + (size_t)s3 * HD)[c];
    acc.x += v0.x; acc.y += v0.y; acc.z += v0.z; acc.w += v0.w;
    acc.x += v1.x; acc.y += v1.y; acc.z += v1.z; acc.w += v1.w;
    acc.x += v2.x; acc.y += v2.y; acc.z += v2.z; acc.w += v2.w;
    acc.x += v3.x; acc.y += v3.y; acc.z += v3.z; acc.w += v3.w;
  }
  for (; j < n; ++j) {
    int s = csr[o + j];
    float4 v = reinterpret_cast<const float4*>(x + (size_t)s * HD)[c];
    acc.x += v.x; acc.y += v.y; acc.z += v.z; acc.w += v.w;
  }
  float inv = 1.0f / (float)max(n, 1);
  float4 m = make_float4(acc.x * inv, acc.y * inv, acc.z * inv, acc.w * inv);
  uint2 ph, pl;
  split4(m, ph, pl);
  reinterpret_cast<uint2*>(oh + (size_t)r * HD)[c] = ph;
  reinterpret_cast<uint2*>(ol + (size_t)r * HD)[c] = pl;
}

// ---------------- L1 gather (paired): split rows (pos-indexed) in, split mean out at batch row ----
__global__ void gather_s2s(const unsigned short* __restrict__ xh0, const unsigned short* __restrict__ xl0,
                           const int* __restrict__ csr0, const int* __restrict__ off0,
                           const int* __restrict__ cnt0, const int* __restrict__ pos0,
                           const int* __restrict__ bidx0,
                           unsigned short* __restrict__ oh0, unsigned short* __restrict__ ol0,
                           const unsigned short* __restrict__ xh1, const unsigned short* __restrict__ xl1,
                           const int* __restrict__ csr1, const int* __restrict__ off1,
                           const int* __restrict__ cnt1, const int* __restrict__ pos1,
                           const int* __restrict__ bidx1,
                           unsigned short* __restrict__ oh1, unsigned short* __restrict__ ol1) {
  const unsigned short *xh, *xl; const int *csr, *offp, *cnt, *pos, *bidx;
  unsigned short *oh, *ol;
  if (blockIdx.y == 0) { xh = xh0; xl = xl0; csr = csr0; offp = off0; cnt = cnt0; pos = pos0; bidx = bidx0; oh = oh0; ol = ol0; }
  else                 { xh = xh1; xl = xl1; csr = csr1; offp = off1; cnt = cnt1; pos = pos1; bidx = bidx1; oh = oh1; ol = ol1; }
  int idx = blockIdx.x * 256 + threadIdx.x;
  int r = idx >> 5, c = idx & 31;
  if (r >= NB) return;
  int g = bidx[r];
  int o = offp[g], n = cnt[g];
  float4 acc = make_float4(0.f, 0.f, 0.f, 0.f);
  auto accum = [&](uint2 hh, uint2 ll) {
    acc.x += __uint_as_float(hh.x << 16) + __uint_as_float(ll.x << 16);
    acc.y += __uint_as_float(hh.x & 0xffff0000u) + __uint_as_float(ll.x & 0xffff0000u);
    acc.z += __uint_as_float(hh.y << 16) + __uint_as_float(ll.y << 16);
    acc.w += __uint_as_float(hh.y & 0xffff0000u) + __uint_as_float(ll.y & 0xffff0000u);
  };
  int j = 0;
  for (; j + 4 <= n; j += 4) {
    int s0 = csr[o + j], s1 = csr[o + j + 1], s2 = csr[o + j + 2], s3 = csr[o + j + 3];
    int p0 = pos[s0], p1 = pos[s1], p2 = pos[s2], p3 = pos[s3];
    uint2 h0 = reinterpret_cast<const uint2*>(xh + (size_t)p0 * HD)[c];
    uint2 l0 = reinterpret_cast<const uint2*>(xl + (size_t)p0 * HD)[c];
    uint2 h1 = reinterpret_cast<const uint2*>(xh + (size_t)p1 * HD)[c];
    uint2 l1 = reinterpret_cast<const uint2*>(xl + (size_t)p1 * HD)[c];
    uint2 h2 = reinterpret_cast<const uint2*>(xh + (size_t)p2 * HD)[c];
    uint2 l2 = reinterpret_cast<const uint2*>(xl + (size_t)p2 * HD)[c];
    uint2 h3 = reinterpret_cast<const uint2*>(xh + (size_t)p3 * HD)[c];
    uint2 l3 = reinterpret_cast<const uint2*>(xl + (size_t)p3 * HD)[c];
    accum(h0, l0); accum(h1, l1); accum(h2, l2); accum(h3, l3);
  }
  for (; j < n; ++j) {
    int p = pos[csr[o + j]];
    uint2 hh = reinterpret_cast<const uint2*>(xh + (size_t)p * HD)[c];
    uint2 ll = reinterpret_cast<const uint2*>(xl + (size_t)p * HD)[c];
    accum(hh, ll);
  }
  float inv = 1.0f / (float)max(n, 1);
  float4 m = make_float4(acc.x * inv, acc.y * inv, acc.z * inv, acc.w * inv);
  uint2 ph, pl;
  split4(m, ph, pl);
  reinterpret_cast<uint2*>(oh + (size_t)r * HD)[c] = ph;
  reinterpret_cast<uint2*>(ol + (size_t)r * HD)[c] = pl;
}

// ---------------- split static weights into B-fragment-swizzled layout ----------------
__global__ void split_weights(const float* __restrict__ Wl, const float* __restrict__ Wr,
                              const float* __restrict__ W2,
                              unsigned short* __restrict__ WLh, unsigned short* __restrict__ WLl,
                              unsigned short* __restrict__ WRh, unsigned short* __restrict__ WRl,
                              unsigned short* __restrict__ W2h, unsigned short* __restrict__ W2l) {
  const int widx[6] = {0, 1, 3, 4, 5, 6};
  int i = blockIdx.x * 256 + threadIdx.x;
  if (i < 98304) {
    int m = i >> 14, e = i & 16383;
    int n = e >> 7, k = e & 127;
    size_t o = (size_t)m * 16384 + swzW(n, k, 128);
    splitf(Wl[(size_t)widx[m] * 16384 + e], WLh[o], WLl[o]);
    splitf(Wr[(size_t)widx[m] * 16384 + e], WRh[o], WRl[o]);
  } else if (i < 131072) {
    int j = i - 98304;
    int n = j >> 8, k = j & 255;
    size_t o = swzW(n, k, 256);
    splitf(W2[j], W2h[o], W2l[o]);
  }
}

// ---------------- MFMA dual GEMM (pairable): LDS-staged X, swizzled W ----------------
struct GemmArgs {
  const unsigned short* X1h; const unsigned short* X1l;
  const unsigned short* X2h; const unsigned short* X2l;  // used when x2f32 == nullptr
  const float* x2f32;                                    // f32 X2 with in-register split
  const unsigned short* Wah; const unsigned short* Wal;  // swizzled (swzW)
  const unsigned short* Wbh; const unsigned short* Wbl;  // swizzled (swzW)
  const float* bias;
  const int* map1; const int* map2;
  const int* nRowsDev;
  unsigned short* Oh; unsigned short* Ol;
  float* Of32;
  int nRowsMax; int K; int Jtot; int relu;
};

template <bool DUAL>
__device__ inline void gemm_body(const GemmArgs& A, int bx, int by, int tid) {
  // LDS: 64 rows x 64-k chunk, +8 ushort pad -> row stride 144B (16B aligned, 2-way banks = free)
  __shared__ unsigned short sX1h[64][72];
  __shared__ unsigned short sX1l[64][72];
  __shared__ unsigned short sX2h[DUAL ? 64 : 1][72];
  __shared__ unsigned short sX2l[DUAL ? 64 : 1][72];

  const int nRows = A.nRowsDev ? *A.nRowsDev : A.nRowsMax;
  const int row0 = bx * 64;
  if (row0 >= nRows) return;
  const int colSlab = by * 128;
  if (colSlab >= A.Jtot) return;
  const int lane = tid & 63;
  const int wv = tid >> 6;
  const int quad = lane >> 4, m16 = lane & 15;
  const int n0 = colSlab + wv * 32;
  const int K = A.K;

  // staging role: 4 threads per row, 16 elements each
  const int sr = tid >> 2;
  const int sk = (tid & 3) * 16;
  int gsrc = row0 + sr;
  if (gsrc > nRows - 1) gsrc = nRows - 1;
  const int sg1 = A.map1 ? A.map1[gsrc] : gsrc;
  const int sg2 = DUAL ? (A.map2 ? A.map2[gsrc] : gsrc) : 0;

  f32x4 acc[4][2];
#pragma unroll
  for (int ct = 0; ct < 2; ++ct) {
    float b = A.bias[n0 + ct * 16 + m16];
    f32x4 bb = {b, b, b, b};
#pragma unroll
    for (int rt = 0; rt < 4; ++rt) acc[rt][ct] = bb;
  }

  for (int kc = 0; kc < K; kc += 64) {
    // ---- stage X chunk into LDS (coalesced) ----
    {
      const unsigned short* p = A.X1h + (size_t)sg1 * K + kc + sk;
      *reinterpret_cast<short8*>(&sX1h[sr][sk])     = *reinterpret_cast<const short8*>(p);
      *reinterpret_cast<short8*>(&sX1h[sr][sk + 8]) = *reinterpret_cast<const short8*>(p + 8);
      const unsigned short* q = A.X1l + (size_t)sg1 * K + kc + sk;
      *reinterpret_cast<short8*>(&sX1l[sr][sk])     = *reinterpret_cast<const short8*>(q);
      *reinterpret_cast<short8*>(&sX1l[sr][sk + 8]) = *reinterpret_cast<const short8*>(q + 8);
    }
    if (DUAL) {
      if (A.x2f32) {
        const float* p = A.x2f32 + (size_t)sg2 * K + kc + sk;
        short8 h0, l0, h1, l1;
        split8(p, h0, l0);
        split8(p + 8, h1, l1);
        *reinterpret_cast<short8*>(&sX2h[sr][sk])     = h0;
        *reinterpret_cast<short8*>(&sX2h[sr][sk + 8]) = h1;
        *reinterpret_cast<short8*>(&sX2l[sr][sk])     = l0;
        *reinterpret_cast<short8*>(&sX2l[sr][sk + 8]) = l1;
      } else {
        const unsigned short* p = A.X2h + (size_t)sg2 * K + kc + sk;
        *reinterpret_cast<short8*>(&sX2h[sr][sk])     = *reinterpret_cast<const short8*>(p);
        *reinterpret_cast<short8*>(&sX2h[sr][sk + 8]) = *reinterpret_cast<const short8*>(p + 8);
        const unsigned short* q = A.X2l + (size_t)sg2 * K + kc + sk;
        *reinterpret_cast<short8*>(&sX2l[sr][sk])     = *reinterpret_cast<const short8*>(q);
        *reinterpret_cast<short8*>(&sX2l[sr][sk + 8]) = *reinterpret_cast<const short8*>(q + 8);
      }
    }
    __syncthreads();

    // ---- compute: 2 MFMA k-steps per chunk ----
#pragma unroll
    for (int kk = 0; kk < 64; kk += 32) {
      const int ktile = (kc + kk) >> 5;
      short8 bah[2], bal[2], bbh[2], bbl[2];
#pragma unroll
      for (int ct = 0; ct < 2; ++ct) {
        size_t wo = ((size_t)(((n0 + ct * 16) >> 4) * (K >> 5) + ktile)) * 512 + (size_t)lane * 8;
        bah[ct] = *reinterpret_cast<const short8*>(A.Wah + wo);
        bal[ct] = *reinterpret_cast<const short8*>(A.Wal + wo);
        if (DUAL) {
          bbh[ct] = *reinterpret_cast<const short8*>(A.Wbh + wo);
          bbl[ct] = *reinterpret_cast<const short8*>(A.Wbl + wo);
        }
      }
#pragma unroll
      for (int rt = 0; rt < 4; ++rt) {
        const int xr = rt * 16 + m16;
        const int xo = kk + quad * 8;
        short8 a1h = *reinterpret_cast<const short8*>(&sX1h[xr][xo]);
        short8 a1l = *reinterpret_cast<const short8*>(&sX1l[xr][xo]);
#pragma unroll
        for (int ct = 0; ct < 2; ++ct) {
          acc[rt][ct] = __builtin_amdgcn_mfma_f32_16x16x32_bf16(a1h, bah[ct], acc[rt][ct], 0, 0, 0);
          acc[rt][ct] = __builtin_amdgcn_mfma_f32_16x16x32_bf16(a1h, bal[ct], acc[rt][ct], 0, 0, 0);
          acc[rt][ct] = __builtin_amdgcn_mfma_f32_16x16x32_bf16(a1l, bah[ct], acc[rt][ct], 0, 0, 0);
        }
        if (DUAL) {
          short8 a2h = *reinterpret_cast<const short8*>(&sX2h[xr][xo]);
          short8 a2l = *reinterpret_cast<const short8*>(&sX2l[xr][xo]);
#pragma unroll
          for (int ct = 0; ct < 2; ++ct) {
            acc[rt][ct] = __builtin_amdgcn_mfma_f32_16x16x32_bf16(a2h, bbh[ct], acc[rt][ct], 0, 0, 0);
            acc[rt][ct] = __builtin_amdgcn_mfma_f32_16x16x32_bf16(a2h, bbl[ct], acc[rt][ct], 0, 0, 0);
            acc[rt][ct] = __builtin_amdgcn_mfma_f32_16x16x32_bf16(a2l, bbh[ct], acc[rt][ct], 0, 0, 0);
          }
        }
      }
    }
    __syncthreads();
  }

  // epilogue: D[m = quad*4+i][n = m16] per 16x16 tile
#pragma unroll
  for (int rt = 0; rt < 4; ++rt) {
#pragma unroll
    for (int i = 0; i < 4; ++i) {
      int m = row0 + rt * 16 + quad * 4 + i;
      if (m < nRows) {
#pragma unroll
        for (int ct = 0; ct < 2; ++ct) {
          float v = acc[rt][ct][i];
          if (A.relu) v = fmaxf(v, 0.0f);
          size_t o = (size_t)m * A.Jtot + n0 + ct * 16 + m16;
          if (A.Of32) A.Of32[o] = v;
          if (A.Oh) {
            unsigned short h, l;
            splitf(v, h, l);
            A.Oh[o] = h; A.Ol[o] = l;
          }
        }
      }
    }
  }
}

template <bool DUAL>
__global__ __launch_bounds__(256) void mfma_pair(GemmArgs a, GemmArgs b, int agx) {
  int bx = blockIdx.x;
  if (bx < agx) gemm_body<DUAL>(a, bx, blockIdx.y, threadIdx.x);
  else          gemm_body<DUAL>(b, bx - agx, blockIdx.y, threadIdx.x);
}

// ---------------- fold attention (len-1 softmax == identity): Wfold = Wout @ Wv ------
__global__ void fold_attn(const float* __restrict__ Win, const float* __restrict__ bin,
                          const float* __restrict__ Wout, const float* __restrict__ bout,
                          float* __restrict__ Wfold, float* __restrict__ bfold) {
  int s = blockIdx.x >> 7, m = blockIdx.x & 127, k = threadIdx.x;
  const float* wout_row = Wout + ((size_t)s * HD + m) * HD;
  const float* wv = Win + (size_t)s * 3 * HD * HD + 2 * HD * HD;
  float acc = 0.0f;
  for (int u = 0; u < HD; ++u) acc += wout_row[u] * wv[u * HD + k];
  Wfold[((size_t)s * HD + m) * HD + k] = acc;
  if (k == 0) {
    const float* bv = bin + (size_t)s * 3 * HD + 2 * HD;
    float b = bout[s * HD + m];
    for (int u = 0; u < HD; ++u) b += wout_row[u] * bv[u];
    bfold[s * HD + m] = b;
  }
}

// ---------------- fold attn into MLP layer 1, emit swizzled split-bf16 A/B ----------------
__global__ void fold_mlp(const float* __restrict__ W1, const float* __restrict__ b1,
                         const float* __restrict__ Wfold, const float* __restrict__ bfold,
                         unsigned short* __restrict__ Ah, unsigned short* __restrict__ Al,
                         unsigned short* __restrict__ Bh, unsigned short* __restrict__ Bl,
                         float* __restrict__ bc) {
  int r = blockIdx.x, k = threadIdx.x;
  const float* w1r = W1 + (size_t)r * 512;
  const float* Wf0 = Wfold;            // module 0: drug_att <- dis_emb
  const float* Wf1 = Wfold + HD * HD;  // module 1: dis_att  <- drug_emb
  float accA = 0.0f, accB = 0.0f;
  for (int m = 0; m < HD; ++m) {
    accA += w1r[384 + m] * Wf1[m * HD + k];
    accB += w1r[256 + m] * Wf0[m * HD + k];
  }
  size_t o = swzW(r, k, 128);
  splitf(w1r[k] + accA, Ah[o], Al[o]);
  splitf(w1r[128 + k] + accB, Bh[o], Bl[o]);
  if (k == 0) {
    float b = b1[r];
    for (int m = 0; m < HD; ++m) b += w1r[256 + m] * bfold[m] + w1r[384 + m] * bfold[HD + m];
    bc[r] = b;
  }
}

// ---------------- final dot: out[b] = h2[b] . W3 + b3 ----------------
__global__ void final_dot(const float* __restrict__ h2, const float* __restrict__ W3,
                          const float* __restrict__ b3, float* __restrict__ out) {
  int b = blockIdx.x * 4 + (threadIdx.x >> 6);
  int lane = threadIdx.x & 63;
  float2 hv = reinterpret_cast<const float2*>(h2 + (size_t)b * HD)[lane];
  float2 wv = reinterpret_cast<const float2*>(W3)[lane];
  float v = hv.x * wv.x + hv.y * wv.y;
  for (int off = 32; off; off >>= 1) v += __shfl_down(v, off);
  if (lane == 0) out[b] = v + b3[0];
}

}  // namespace

extern "C" void kernel_launch(void* const* d_in, const int* in_sizes, int n_in,
                              void* d_out, int out_size, void* d_ws, size_t ws_size,
                              hipStream_t stream) {
  const int* src_d2di  = (const int*)d_in[0];
  const int* dst_d2di  = (const int*)d_in[1];
  const int* src_di2dr = (const int*)d_in[2];
  const int* dst_di2dr = (const int*)d_in[3];
  const int* drug_idx  = (const int*)d_in[4];
  const int* dis_idx   = (const int*)d_in[5];
  const float* emb_drug = (const float*)d_in[6];
  const float* emb_dis  = (const float*)d_in[7];
  const float* Wl = (const float*)d_in[8];
  const float* bl = (const float*)d_in[9];
  const float* Wr = (const float*)d_in[10];
  const float* attn_Win  = (const float*)d_in[11];
  const float* attn_bin  = (const float*)d_in[12];
  const float* attn_Wout = (const float*)d_in[13];
  const float* attn_bout = (const float*)d_in[14];
  const float* W1 = (const float*)d_in[15];
  const float* b1 = (const float*)d_in[16];
  const float* W2 = (const float*)d_in[17];
  const float* b2 = (const float*)d_in[18];
  const float* W3 = (const float*)d_in[19];
  const float* b3 = (const float*)d_in[20];
  float* out = (float*)d_out;

  // ---- workspace carve (16B-aligned float units) ----
  float* ws = (float*)d_ws;
  size_t off = 0;
  auto carve = [&](size_t nfloats) {
    float* p = ws + off;
    off += (nfloats + 3) & ~(size_t)3;
    return p;
  };
  auto carveU = [&](size_t nush) { return (unsigned short*)carve((nush + 1) / 2); };

  // zeroed region (one memset): cnt/cursor ints + uchar flags + nctr
  int* cnt_dis     = (int*)carve(NDI);
  int* cnt_drug    = (int*)carve(NDR);
  int* cursor_dis  = (int*)carve(NDI);
  int* cursor_drug = (int*)carve(NDR);
  unsigned char* fb_dis  = (unsigned char*)carve((NDI + 3) / 4);
  unsigned char* fb_drug = (unsigned char*)carve((NDR + 3) / 4);
  unsigned char* fd_dis  = (unsigned char*)carve((NDI + 3) / 4);
  unsigned char* fd_drug = (unsigned char*)carve((NDR + 3) / 4);
  int* nctr        = (int*)carve(8);       // [0]=n_list_dis, [1]=n_list_drug
  const size_t zero_bytes = off * sizeof(float);
  // not zeroed
  int* off_dis   = (int*)carve(NDI);
  int* off_drug  = (int*)carve(NDR);
  int* list_dis  = (int*)carve(NDI);
  int* list_drug = (int*)carve(NDR);
  int* pos_dis   = (int*)carve(NDI);
  int* pos_drug  = (int*)carve(NDR);
  int* csr_d2di  = (int*)carve(NE);
  int* csr_di2dr = (int*)carve(NE);
  int* bsum_dis  = (int*)carve(256);
  int* bsum_drug = (int*)carve(256);
  int* bp_drug   = (int*)carve(NB);
  int* bp_dis    = (int*)carve(NB);

  // big split-bf16 buffers (compact, list-position indexed)
  unsigned short* aggh_dis  = carveU((size_t)NDI * HD);  // L0 agg -> overwritten in place by dis1_s0
  unsigned short* aggl_dis  = carveU((size_t)NDI * HD);
  unsigned short* aggh_drug = carveU((size_t)NDR * HD);  // L0 agg -> overwritten in place by drug1_s1
  unsigned short* aggl_drug = carveU((size_t)NDR * HD);
  // batch-sized split buffers
  unsigned short* d1bh = carveU((size_t)NB * HD);  // drug1 (stack0) at batch rows
  unsigned short* d1bl = carveU((size_t)NB * HD);
  unsigned short* s1bh = carveU((size_t)NB * HD);  // dis1 (stack1) at batch rows
  unsigned short* s1bl = carveU((size_t)NB * HD);
  unsigned short* aBdrh = carveU((size_t)NB * HD); // L1 agg at batch drug rows
  unsigned short* aBdrl = carveU((size_t)NB * HD);
  unsigned short* aBdih = carveU((size_t)NB * HD); // L1 agg at batch disease rows
  unsigned short* aBdil = carveU((size_t)NB * HD);
  unsigned short* deh = carveU((size_t)NB * HD);   // drug_emb split
  unsigned short* del = carveU((size_t)NB * HD);
  unsigned short* seh = carveU((size_t)NB * HD);   // dis_emb split
  unsigned short* sel = carveU((size_t)NB * HD);
  unsigned short* h1h = carveU((size_t)NB * 2 * HD);
  unsigned short* h1l = carveU((size_t)NB * 2 * HD);
  // weights (split, B-fragment swizzled)
  unsigned short* WLh = carveU(6 * 16384);
  unsigned short* WLl = carveU(6 * 16384);
  unsigned short* WRh = carveU(6 * 16384);
  unsigned short* WRl = carveU(6 * 16384);
  unsigned short* W2h = carveU(32768);
  unsigned short* W2l = carveU(32768);
  unsigned short* Amh = carveU(32768);
  unsigned short* Aml = carveU(32768);
  unsigned short* Bmh = carveU(32768);
  unsigned short* Bml = carveU(32768);
  // f32 small
  float* Wfold = carve(2 * HD * HD);
  float* bfold = carve(2 * HD);
  float* bc    = carve(2 * HD);
  float* h2    = carve((size_t)NB * HD);

  dim3 blk(256);
  const size_t WS = 16384;  // one 128x128 weight slot (elements)
  const int EB = (NE + 255) / 256;

  hipMemsetAsync(cnt_dis, 0, zero_bytes, stream);

  // weight prep (independent of graph work)
  fold_attn<<<256, 128, 0, stream>>>(attn_Win, attn_bin, attn_Wout, attn_bout, Wfold, bfold);
  fold_mlp<<<256, 128, 0, stream>>>(W1, b1, Wfold, bfold, Amh, Aml, Bmh, Bml, bc);
  split_weights<<<512, blk, 0, stream>>>(Wl, Wr, W2, WLh, WLl, WRh, WRl, W2h, W2l);

  // demand marking (edge-parallel, no CSR needed)
  batch_mark<<<(2 * NB + 255) / 256, blk, 0, stream>>>(drug_idx, dis_idx, fb_drug, fb_dis, fd_drug, fd_dis);
  edge_mark<<<dim3(EB, 2), blk, 0, stream>>>(src_d2di, dst_d2di, src_di2dr, dst_di2dr,
                                             fb_dis, fb_drug, fd_drug, fd_dis);

  // filtered degree counts, scans, filtered CSR
  count_f<<<dim3(EB, 2), blk, 0, stream>>>(dst_d2di, dst_di2dr, fd_dis, fd_drug, cnt_dis, cnt_drug);
  scan1y<<<dim3((NDR + 1023) / 1024, 2), blk, 0, stream>>>(cnt_dis, NDI, off_dis, bsum_dis,
                                                           cnt_drug, NDR, off_drug, bsum_drug);
  scan2<<<2, blk, 0, stream>>>(bsum_dis, (NDI + 1023) / 1024, bsum_drug, (NDR + 1023) / 1024);
  scan3y<<<dim3((NDR + 255) / 256, 2), blk, 0, stream>>>(off_dis, NDI, bsum_dis, off_drug, NDR, bsum_drug);
  csr_f<<<dim3(EB, 2), blk, 0, stream>>>(src_d2di, dst_d2di, src_di2dr, dst_di2dr, NE,
                                         fd_dis, fd_drug,
                                         off_dis, cursor_dis, csr_d2di,
                                         off_drug, cursor_drug, csr_di2dr);

  // compact demand flags -> lists + positions; batch positions
  compact2<<<dim3((NDR + 255) / 256, 2), blk, 0, stream>>>(fd_dis, NDI, list_dis, pos_dis, nctr + 0,
                                                           fd_drug, NDR, list_drug, pos_drug, nctr + 1);
  batchpos_k<<<(2 * NB + 255) / 256, blk, 0, stream>>>(drug_idx, dis_idx, pos_drug, pos_dis, bp_drug, bp_dis);

  // layer-0 mean aggregation at list positions (both directions, one dispatch)
  gather_f2s<<<dim3((NDR * 32 + 255) / 256, 2), blk, 0, stream>>>(
      emb_drug, csr_d2di, off_dis, cnt_dis, list_dis, nctr + 0, aggh_dis, aggl_dis,
      emb_dis, csr_di2dr, off_drug, cnt_drug, list_drug, nctr + 1, aggh_drug, aggl_drug);

  GemmArgs z{};  // zero template
  auto mk = [&](const unsigned short* X1h_, const unsigned short* X1l_,
                const unsigned short* X2h_, const unsigned short* X2l_, const float* x2f,
                const unsigned short* Wah_, const unsigned short* Wal_,
                const unsigned short* Wbh_, const unsigned short* Wbl_,
                const float* bias_, const int* map1_, const int* map2_, const int* nDev,
                unsigned short* Oh_, unsigned short* Ol_, float* Of_,
                int nMax, int K_, int J_, int relu_) {
    GemmArgs g = z;
    g.X1h = X1h_; g.X1l = X1l_; g.X2h = X2h_; g.X2l = X2l_; g.x2f32 = x2f;
    g.Wah = Wah_; g.Wal = Wal_; g.Wbh = Wbh_; g.Wbl = Wbl_;
    g.bias = bias_; g.map1 = map1_; g.map2 = map2_; g.nRowsDev = nDev;
    g.Oh = Oh_; g.Ol = Ol_; g.Of32 = Of_;
    g.nRowsMax = nMax; g.K = K_; g.Jtot = J_; g.relu = relu_;
    return g;
  };

  // L0 batch pair: dis1b (stack1, W idx4 -> slot3) + drug1b (stack0, W idx1 -> slot1)
  {
    GemmArgs a = mk(aggh_dis, aggl_dis, nullptr, nullptr, emb_dis,
                    WLh + 3 * WS, WLl + 3 * WS, WRh + 3 * WS, WRl + 3 * WS, bl + 4 * HD,
                    bp_dis, dis_idx, nullptr, s1bh, s1bl, nullptr, NB, 128, 128, 1);
    GemmArgs b = mk(aggh_drug, aggl_drug, nullptr, nullptr, emb_drug,
                    WLh + 1 * WS, WLl + 1 * WS, WRh + 1 * WS, WRl + 1 * WS, bl + 1 * HD,
                    bp_drug, drug_idx, nullptr, d1bh, d1bl, nullptr, NB, 128, 128, 1);
    mfma_pair<true><<<dim3(NB / 64 * 2, 1), blk, 0, stream>>>(a, b, NB / 64);
  }

  // L0 list pair (in-place over agg buffers): dis1_s0 (slot0) + drug1_s1 (slot4)
  {
    const int agx = (NDI + 63) / 64, bgx = (NDR + 63) / 64;
    GemmArgs a = mk(aggh_dis, aggl_dis, nullptr, nullptr, emb_dis,
                    WLh + 0 * WS, WLl + 0 * WS, WRh + 0 * WS, WRl + 0 * WS, bl + 0 * HD,
                    nullptr, list_dis, nctr + 0, aggh_dis, aggl_dis, nullptr, NDI, 128, 128, 1);
    GemmArgs b = mk(aggh_drug, aggl_drug, nullptr, nullptr, emb_drug,
                    WLh + 4 * WS, WLl + 4 * WS, WRh + 4 * WS, WRl + 4 * WS, bl + 5 * HD,
                    nullptr, list_drug, nctr + 1, aggh_drug, aggl_drug, nullptr, NDR, 128, 128, 1);
    mfma_pair<true><<<dim3(agx + bgx, 1), blk, 0, stream>>>(a, b, agx);
  }

  // layer-1 mean aggregation at batch rows (agg buffers now hold transformed L0 outputs)
  gather_s2s<<<dim3((NB * 32) / 256, 2), blk, 0, stream>>>(
      aggh_dis, aggl_dis, csr_di2dr, off_drug, cnt_drug, pos_dis, drug_idx, aBdrh, aBdrl,
      aggh_drug, aggl_drug, csr_d2di, off_dis, cnt_dis, pos_drug, dis_idx, aBdih, aBdil);

  // L1 pair: drug_emb (W idx3 -> slot2) + dis_emb (W idx6 -> slot5)
  {
    GemmArgs a = mk(aBdrh, aBdrl, d1bh, d1bl, nullptr,
                    WLh + 2 * WS, WLl + 2 * WS, WRh + 2 * WS, WRl + 2 * WS, bl + 3 * HD,
                    nullptr, nullptr, nullptr, deh, del, nullptr, NB, 128, 128, 1);
    GemmArgs b = mk(aBdih, aBdil, s1bh, s1bl, nullptr,
                    WLh + 5 * WS, WLl + 5 * WS, WRh + 5 * WS, WRl + 5 * WS, bl + 6 * HD,
                    nullptr, nullptr, nullptr, seh, sel, nullptr, NB, 128, 128, 1);
    mfma_pair<true><<<dim3(NB / 64 * 2, 1), blk, 0, stream>>>(a, b, NB / 64);
  }

  // link MLP (attention folded into Am/Bm/bc)
  {
    GemmArgs a = mk(deh, del, seh, sel, nullptr,
                    Amh, Aml, Bmh, Bml, bc,
                    nullptr, nullptr, nullptr, h1h, h1l, nullptr, NB, 128, 256, 1);
    mfma_pair<true><<<dim3(NB / 64, 2), blk, 0, stream>>>(a, a, NB / 64);
  }
  {
    GemmArgs a = mk(h1h, h1l, nullptr, nullptr, nullptr,
                    W2h, W2l, nullptr, nullptr, b2,
                    nullptr, nullptr, nullptr, nullptr, nullptr, h2, NB, 256, 128, 1);
    mfma_pair<false><<<dim3(NB / 64, 1), blk, 0, stream>>>(a, a, NB / 64);
  }
  final_dot<<<NB / 4, blk, 0, stream>>>(h2, W3, b3, out);

  (void)in_sizes; (void)n_in; (void)out_size; (void)ws_size;
}